// Round 9
// baseline (212.713 us; speedup 1.0000x reference)
//
#include <hip/hip_runtime.h>
#include <math.h>

#define BSZ   8
#define NSEQ  1024
#define DIM   512
#define NH    8
#define DH    64
#define INNER 512
#define NTOK  (BSZ*NSEQ)     // 8192
#define QKVN  (3*INNER)      // 1536

typedef __bf16 bf16x8 __attribute__((ext_vector_type(8)));
typedef float  f32x4  __attribute__((ext_vector_type(4)));

// q pre-scale: softmax scale (DH^-0.5 = 0.125) folded with log2(e)
#define QSCL (0.125f * 1.44269504088896f)

static __device__ __forceinline__ ushort f2bf(float f) {
    union { float f; unsigned u; } v; v.f = f;
    unsigned r = (v.u + 0x7FFFu + ((v.u >> 16) & 1u)) >> 16;  // RNE
    return (ushort)r;
}
static __device__ __forceinline__ float bf2f(ushort u) {
    union { unsigned u; float f; } v; v.u = ((unsigned)u) << 16;
    return v.f;
}
static __device__ __forceinline__ void split2(float x, ushort& h, ushort& l) {
    h = f2bf(x);
    l = f2bf(x - bf2f(h));
}
// async global->LDS DMA, 16B per lane; LDS dest = wave-uniform base + lane*16
static __device__ __forceinline__ void async16(const void* g, void* l) {
    __builtin_amdgcn_global_load_lds(
        (const __attribute__((address_space(1))) unsigned int*)g,
        (__attribute__((address_space(3))) unsigned int*)l, 16, 0, 0);
}

// ---------------------------------------------------------------------------
// Elementwise fp32 -> bf16 hi/lo split (x)
// ---------------------------------------------------------------------------
__global__ __launch_bounds__(256) void split_cvt_kernel(
    const float* __restrict__ in, ushort* __restrict__ oh, ushort* __restrict__ ol)
{
    const int i = blockIdx.x * 256 + threadIdx.x;
    float4 v = ((const float4*)in)[i];
    ushort4 h, l;
    split2(v.x, h.x, l.x); split2(v.y, h.y, l.y);
    split2(v.z, h.z, l.z); split2(v.w, h.w, l.w);
    ((ushort4*)oh)[i] = h;
    ((ushort4*)ol)[i] = l;
}

// ---------------------------------------------------------------------------
// Transpose + split: in [K][F] fp32 row-major -> outh/outl [F][K] bf16
// ---------------------------------------------------------------------------
__global__ __launch_bounds__(256) void tconv_split_kernel(
    const float* __restrict__ in, ushort* __restrict__ outh,
    ushort* __restrict__ outl, int K, int F)
{
    __shared__ float tile[32][33];
    const int bx = blockIdx.x;           // F/32
    const int by = blockIdx.y;           // K/32
    const int lx = threadIdx.x & 31, ly = threadIdx.x >> 5;
#pragma unroll
    for (int u = 0; u < 4; u++) {
        const int k = by*32 + ly + u*8;
        tile[ly + u*8][lx] = in[(size_t)k*F + bx*32 + lx];
    }
    __syncthreads();
#pragma unroll
    for (int u = 0; u < 4; u++) {
        const int f = bx*32 + ly + u*8;
        ushort h, l;
        split2(tile[lx][ly + u*8], h, l);
        outh[(size_t)f*K + by*32 + lx] = h;
        outl[(size_t)f*K + by*32 + lx] = l;
    }
}

// ---------------------------------------------------------------------------
// V transpose: vb [BH][N][DH] bf16 -> vt [BH][DH][N] bf16. 64x64 tiles.
// ---------------------------------------------------------------------------
__global__ __launch_bounds__(256) void vtrans_kernel(
    const ushort* __restrict__ vb, ushort* __restrict__ vt)
{
    __shared__ ushort tile[64][72];
    const int nt = blockIdx.x;           // 16
    const int bh = blockIdx.y;           // 64
    const int tid = threadIdx.x;
    const ushort* src = vb + (size_t)bh*NSEQ*DH + (size_t)nt*64*DH;
    ushort* dst = vt + (size_t)bh*DH*NSEQ + nt*64;

#pragma unroll
    for (int u = 0; u < 2; u++) {
        const int idx = tid + u*256;         // uint4 index (512 total)
        const int row = idx >> 3;            // 64 rows, 8 uint4/row
        const int col = (idx & 7) * 8;
        *(uint4*)&tile[row][col] = *(const uint4*)(src + row*DH + col);
    }
    __syncthreads();
#pragma unroll
    for (int u = 0; u < 2; u++) {
        const int idx = tid + u*256;
        const int d   = idx >> 3;
        const int n0  = (idx & 7) * 8;
        ushort tmp[8];
#pragma unroll
        for (int i = 0; i < 8; i++) tmp[i] = tile[n0+i][d];
        *(uint4*)&dst[(size_t)d*NSEQ + n0] = *(uint4*)tmp;
    }
}

// ---------------------------------------------------------------------------
// Kernel 1: qkv^T split-bf16 MFMA GEMM, async-DMA fragment-ordered staging.
// 128x128 tile, BK=32, double-buffered (1 barrier/chunk). LDS = 2 x 32 segs
// x 1KB; seg s holds the (part, 16-row group) sub-tile with lane L's MFMA
// fragment at s*1024 + L*16 (DMA writes, conflict-free linear reads).
// parts: 0..7 Ah, 8..15 Al, 16..23 Bh, 24..31 Bl; wave w stages part w.
// ---------------------------------------------------------------------------
__global__ __launch_bounds__(256) void qkv_gemm_split(
    const ushort* __restrict__ Agh, const ushort* __restrict__ Agl,
    const ushort* __restrict__ Bgh, const ushort* __restrict__ Bgl,
    const float* __restrict__ bias, const float* __restrict__ rot,
    const float* __restrict__ trans,
    ushort* __restrict__ qb, ushort* __restrict__ kb, ushort* __restrict__ vb)
{
    extern __shared__ __align__(16) char smem[];   // 65536 B

    const int tid  = threadIdx.x;
    const int lane = tid & 63;
    const int w    = tid >> 6;
    const int c    = lane & 15;
    const int quad = lane >> 4;
    const int wr   = w >> 1, wc = w & 1;
    const int tn   = blockIdx.x;   // token tile (64)
    const int tf   = blockIdx.y;   // feature tile (12)

    f32x4 acc[4][4] = {};

    const ushort* wp = (w == 0) ? Agh : (w == 1) ? Agl : (w == 2) ? Bgh : Bgl;
    const ushort* wbase = wp + (size_t)((w < 2 ? tf : tn)*128 + c)*DIM + quad*8;

    auto stage = [&](int k0, int buf) {
#pragma unroll
        for (int g = 0; g < 8; g++)
            async16(wbase + (size_t)g*16*DIM + k0,
                    smem + buf*32768 + (w*8 + g)*1024);
    };

    stage(0, 0);
    __syncthreads();

    for (int ch = 0; ch < 16; ch++) {
        const int cur = ch & 1, nxt = cur ^ 1;
        if (ch < 15) stage((ch+1)*32, nxt);

        const char* B = smem + cur*32768;
        bf16x8 fah[4], fal[4], fbh[4], fbl[4];
#pragma unroll
        for (int i = 0; i < 4; i++) {
            fah[i] = *(const bf16x8*)(B + ( 0 + wr*4 + i)*1024 + lane*16);
            fal[i] = *(const bf16x8*)(B + ( 8 + wr*4 + i)*1024 + lane*16);
        }
#pragma unroll
        for (int j = 0; j < 4; j++) {
            fbh[j] = *(const bf16x8*)(B + (16 + wc*4 + j)*1024 + lane*16);
            fbl[j] = *(const bf16x8*)(B + (24 + wc*4 + j)*1024 + lane*16);
        }
#pragma unroll
        for (int i = 0; i < 4; i++)
#pragma unroll
            for (int j = 0; j < 4; j++) {
                acc[i][j] = __builtin_amdgcn_mfma_f32_16x16x32_bf16(
                    fah[i], fbh[j], acc[i][j], 0, 0, 0);
                acc[i][j] = __builtin_amdgcn_mfma_f32_16x16x32_bf16(
                    fah[i], fbl[j], acc[i][j], 0, 0, 0);
                acc[i][j] = __builtin_amdgcn_mfma_f32_16x16x32_bf16(
                    fal[i], fbh[j], acc[i][j], 0, 0, 0);
            }
        __syncthreads();
    }

    // epilogue: bias + SE(3) pose + scatter (verified mapping)
    const int sec = tf >> 2;          // 0=q 1=k 2=v (block-uniform)
    ushort* dstbuf = (sec == 0) ? qb : ((sec == 1) ? kb : vb);

#pragma unroll
    for (int j = 0; j < 4; j++) {
        const int tc = tn*128 + wc*64 + j*16 + c;
        const int bb = tc >> 10, n = tc & 1023;
        const float* R = rot   + (size_t)(bb*NSEQ + n)*9;
        const float* T = trans + (size_t)(bb*NSEQ + n)*3;
        const float R0=R[0],R1=R[1],R2=R[2],R3=R[3],R4=R[4],R5=R[5],R6=R[6],R7=R[7],R8=R[8];
        const float T0=T[0],T1=T[1],T2=T[2];
        float ti0 = 0.f, ti1 = 0.f, ti2 = 0.f;
        if (sec == 0) {
            ti0 = -(R0*T0 + R3*T1 + R6*T2);
            ti1 = -(R1*T0 + R4*T1 + R7*T2);
            ti2 = -(R2*T0 + R5*T1 + R8*T2);
        }
#pragma unroll
        for (int i = 0; i < 4; i++) {
            const int fr = tf*128 + wr*64 + i*16 + quad*4;
            const int fl = fr & 511;
            const int h  = fl >> 6, d = fl & 63;
            float4 bv = *(const float4*)(bias + fr);
            const float g0 = acc[i][j][0] + bv.x;
            const float g1 = acc[i][j][1] + bv.y;
            const float g2 = acc[i][j][2] + bv.z;
            const float g3 = acc[i][j][3] + bv.w;
            float o0, o1, o2, o3;
            if (sec == 0) {
                o0 = (R0*g0 + R1*g1 + R2*g2) * QSCL;
                o1 = (R3*g0 + R4*g1 + R5*g2) * QSCL;
                o2 = (R6*g0 + R7*g1 + R8*g2) * QSCL;
                o3 = (ti0*g0 + ti1*g1 + ti2*g2 + g3) * QSCL;
            } else {
                o0 = R0*g0 + R1*g1 + R2*g2 + T0*g3;
                o1 = R3*g0 + R4*g1 + R5*g2 + T1*g3;
                o2 = R6*g0 + R7*g1 + R8*g2 + T2*g3;
                o3 = g3;
            }
            ushort4 ov = { f2bf(o0), f2bf(o1), f2bf(o2), f2bf(o3) };
            *(ushort4*)(dstbuf + ((size_t)((bb*NH + h)*NSEQ + n))*DH + d) = ov;
        }
    }
}

// ---------------------------------------------------------------------------
// Kernel 2: async-pipelined MFMA flash attention (R8, unchanged).
// ---------------------------------------------------------------------------
__global__ __launch_bounds__(256) void attn_mfma_kernel(
    const ushort* __restrict__ qb, const ushort* __restrict__ kb,
    const ushort* __restrict__ vt, const float* __restrict__ rot,
    const float* __restrict__ trans,
    ushort* __restrict__ omh, ushort* __restrict__ oml)
{
    __shared__ __align__(16) char smem[51200];

    const int tid  = threadIdx.x;
    const int lane = tid & 63;
    const int w    = tid >> 6;
    const int c    = lane & 15;
    const int quad = lane >> 4;

    const int qt = blockIdx.x;      // 0..7 (128 q rows)
    const int bh = blockIdx.y;      // 0..63
    const int bb = bh >> 3, h = bh & 7;

    const ushort* Q = qb + (size_t)bh * NSEQ * DH;
    const ushort* K = kb + (size_t)bh * NSEQ * DH;
    const ushort* V = vt + (size_t)bh * DH * NSEQ;   // [DH][NSEQ]

    bf16x8 qf[2][2];
#pragma unroll
    for (int m = 0; m < 2; m++) {
        const ushort* qrow = Q + (size_t)(qt*128 + w*32 + m*16 + c)*DH + quad*8;
        qf[m][0] = *(const bf16x8*)(qrow);
        qf[m][1] = *(const bf16x8*)(qrow + 32);
    }

    f32x4 Oacc[2][4] = {};
    float lsum[2][4] = {};

    auto stage = [&](int kt, int buf) {
#pragma unroll
        for (int u = 0; u < 2; u++) {            // K segs
            const int seg = w + u*4;             // 0..7
            const int nt = seg >> 1, hh = seg & 1;
            const ushort* g = K + (size_t)(kt*64 + nt*16 + c)*DH + hh*32 + quad*8;
            async16(g, smem + buf*16384 + seg*1024);
        }
#pragma unroll
        for (int u = 0; u < 2; u++) {            // V segs
            const int s2 = w + u*4;              // 0..7
            const int nt = s2 >> 1, kc = s2 & 1;
            const ushort* g = V + (size_t)(nt*16 + c)*NSEQ + kt*64 + kc*32 + quad*8;
            async16(g, smem + buf*16384 + 8192 + s2*1024);
        }
    };

    stage(0, 0);
    __syncthreads();

    for (int kt = 0; kt < 16; kt++) {
        const int cur = kt & 1, nxt = cur ^ 1;
        if (kt < 15) stage(kt+1, nxt);

        const char* Kb = smem + cur*16384;
        const char* Vb = smem + cur*16384 + 8192;

        f32x4 s[2][4];
#pragma unroll
        for (int nt = 0; nt < 4; nt++) {
            bf16x8 k0 = *(const bf16x8*)(Kb + (nt*2+0)*1024 + lane*16);
            bf16x8 k1 = *(const bf16x8*)(Kb + (nt*2+1)*1024 + lane*16);
#pragma unroll
            for (int m = 0; m < 2; m++) {
                f32x4 a = {0.f, 0.f, 0.f, 0.f};
                a = __builtin_amdgcn_mfma_f32_16x16x32_bf16(qf[m][0], k0, a, 0, 0, 0);
                a = __builtin_amdgcn_mfma_f32_16x16x32_bf16(qf[m][1], k1, a, 0, 0, 0);
                s[m][nt] = a;
            }
        }

#pragma unroll
        for (int m = 0; m < 2; m++) {
            ushort (*Psw)[72] = (ushort (*)[72])(smem + 32768 + (w*2+m)*2304);
#pragma unroll
            for (int nt = 0; nt < 4; nt++)
#pragma unroll
                for (int r = 0; r < 4; r++) {
                    const float p = exp2f(s[m][nt][r]);
                    lsum[m][r] += p;
                    Psw[quad*4 + r][nt*16 + c] = (ushort)__builtin_bit_cast(
                        unsigned short, (__bf16)p);
                }
        }
        __asm__ volatile("s_waitcnt lgkmcnt(0)" ::: "memory");

#pragma unroll
        for (int kc = 0; kc < 2; kc++) {
            bf16x8 vfr[4];
#pragma unroll
            for (int nt = 0; nt < 4; nt++)
                vfr[nt] = *(const bf16x8*)(Vb + (nt*2+kc)*1024 + lane*16);
#pragma unroll
            for (int m = 0; m < 2; m++) {
                ushort (*Psw)[72] = (ushort (*)[72])(smem + 32768 + (w*2+m)*2304);
                bf16x8 a = *(const bf16x8*)&Psw[c][kc*32 + quad*8];
#pragma unroll
                for (int nt = 0; nt < 4; nt++)
                    Oacc[m][nt] = __builtin_amdgcn_mfma_f32_16x16x32_bf16(
                        a, vfr[nt], Oacc[m][nt], 0, 0, 0);
            }
        }
        __syncthreads();
    }

#pragma unroll
    for (int mk = 1; mk < 16; mk <<= 1)
#pragma unroll
        for (int m = 0; m < 2; m++)
#pragma unroll
            for (int r = 0; r < 4; r++)
                lsum[m][r] += __shfl_xor(lsum[m][r], mk);

    float (*Osh)[68] = (float (*)[68])smem;   // [128][68]
    {
        float inv[2][4];
#pragma unroll
        for (int m = 0; m < 2; m++)
#pragma unroll
            for (int r = 0; r < 4; r++) inv[m][r] = 1.f / lsum[m][r];
#pragma unroll
        for (int m = 0; m < 2; m++)
#pragma unroll
            for (int nt = 0; nt < 4; nt++)
#pragma unroll
                for (int r = 0; r < 4; r++)
                    Osh[w*32 + m*16 + quad*4 + r][nt*16 + c] =
                        Oacc[m][nt][r] * inv[m][r];
    }
    __syncthreads();

#pragma unroll
    for (int u = 0; u < 8; u++) {
        const int t   = tid + u*256;       // 0..2047
        const int row = t >> 4;            // 0..127
        const int g   = t & 15;
        const int n   = qt*128 + row;
        const float o0 = Osh[row][g*4+0], o1 = Osh[row][g*4+1];
        const float o2 = Osh[row][g*4+2], o3 = Osh[row][g*4+3];
        const float* R = rot   + (size_t)(bb*NSEQ + n)*9;
        const float* T = trans + (size_t)(bb*NSEQ + n)*3;
        const float ti0 = -(R[0]*T[0] + R[3]*T[1] + R[6]*T[2]);
        const float ti1 = -(R[1]*T[0] + R[4]*T[1] + R[7]*T[2]);
        const float ti2 = -(R[2]*T[0] + R[5]*T[1] + R[8]*T[2]);
        const float p0 = R[0]*o0 + R[3]*o1 + R[6]*o2 + ti0*o3;
        const float p1 = R[1]*o0 + R[4]*o1 + R[7]*o2 + ti1*o3;
        const float p2 = R[2]*o0 + R[5]*o1 + R[8]*o2 + ti2*o3;
        const float p3 = o3;
        ushort4 hv, lv;
        split2(p0, hv.x, lv.x); split2(p1, hv.y, lv.y);
        split2(p2, hv.z, lv.z); split2(p3, hv.w, lv.w);
        const size_t idx = (size_t)(bb*NSEQ + n)*INNER + h*DH + g*4;
        *(ushort4*)(omh + idx) = hv;
        *(ushort4*)(oml + idx) = lv;
    }
}

// ---------------------------------------------------------------------------
// Kernel 3: out^T split-bf16 MFMA GEMM, async-DMA staging (same as kernel 1).
// ---------------------------------------------------------------------------
__global__ __launch_bounds__(256) void out_gemm_split(
    const ushort* __restrict__ Agh, const ushort* __restrict__ Agl,
    const ushort* __restrict__ Bgh, const ushort* __restrict__ Bgl,
    const float* __restrict__ bias, float* __restrict__ out)
{
    extern __shared__ __align__(16) char smem[];   // 65536 B

    const int tid  = threadIdx.x;
    const int lane = tid & 63;
    const int w    = tid >> 6;
    const int c    = lane & 15;
    const int quad = lane >> 4;
    const int wr   = w >> 1, wc = w & 1;
    const int tn   = blockIdx.x;   // token tile (64)
    const int tf   = blockIdx.y;   // feature tile (4)

    f32x4 acc[4][4] = {};

    const ushort* wp = (w == 0) ? Agh : (w == 1) ? Agl : (w == 2) ? Bgh : Bgl;
    const ushort* wbase = wp + (size_t)((w < 2 ? tf : tn)*128 + c)*INNER + quad*8;

    auto stage = [&](int k0, int buf) {
#pragma unroll
        for (int g = 0; g < 8; g++)
            async16(wbase + (size_t)g*16*INNER + k0,
                    smem + buf*32768 + (w*8 + g)*1024);
    };

    stage(0, 0);
    __syncthreads();

    for (int ch = 0; ch < 16; ch++) {
        const int cur = ch & 1, nxt = cur ^ 1;
        if (ch < 15) stage((ch+1)*32, nxt);

        const char* B = smem + cur*32768;
        bf16x8 fah[4], fal[4], fbh[4], fbl[4];
#pragma unroll
        for (int i = 0; i < 4; i++) {
            fah[i] = *(const bf16x8*)(B + ( 0 + wr*4 + i)*1024 + lane*16);
            fal[i] = *(const bf16x8*)(B + ( 8 + wr*4 + i)*1024 + lane*16);
        }
#pragma unroll
        for (int j = 0; j < 4; j++) {
            fbh[j] = *(const bf16x8*)(B + (16 + wc*4 + j)*1024 + lane*16);
            fbl[j] = *(const bf16x8*)(B + (24 + wc*4 + j)*1024 + lane*16);
        }
#pragma unroll
        for (int i = 0; i < 4; i++)
#pragma unroll
            for (int j = 0; j < 4; j++) {
                acc[i][j] = __builtin_amdgcn_mfma_f32_16x16x32_bf16(
                    fah[i], fbh[j], acc[i][j], 0, 0, 0);
                acc[i][j] = __builtin_amdgcn_mfma_f32_16x16x32_bf16(
                    fah[i], fbl[j], acc[i][j], 0, 0, 0);
                acc[i][j] = __builtin_amdgcn_mfma_f32_16x16x32_bf16(
                    fal[i], fbh[j], acc[i][j], 0, 0, 0);
            }
        __syncthreads();
    }

#pragma unroll
    for (int j = 0; j < 4; j++) {
        const int tc = tn*128 + wc*64 + j*16 + c;
#pragma unroll
        for (int i = 0; i < 4; i++) {
            const int fr = tf*128 + wr*64 + i*16 + quad*4;
            float4 bv = *(const float4*)(bias + fr);
            float4 ov = { acc[i][j][0] + bv.x, acc[i][j][1] + bv.y,
                          acc[i][j][2] + bv.z, acc[i][j][3] + bv.w };
            *(float4*)(out + (size_t)tc*DIM + fr) = ov;
        }
    }
}

extern "C" void kernel_launch(void* const* d_in, const int* in_sizes, int n_in,
                              void* d_out, int out_size, void* d_ws, size_t ws_size,
                              hipStream_t stream) {
    (void)in_sizes; (void)n_in; (void)out_size; (void)ws_size;
    const float* x     = (const float*)d_in[0];
    const float* rot   = (const float*)d_in[1];
    const float* trans = (const float*)d_in[2];
    const float* w_qkv = (const float*)d_in[3];
    const float* b_qkv = (const float*)d_in[4];
    const float* w_out = (const float*)d_in[5];
    const float* b_out = (const float*)d_in[6];
    float* out = (float*)d_out;

    const size_t HB = (size_t)BSZ*NH*NSEQ*DH;        // 4,194,304 elements
    ushort* qb   = (ushort*)d_ws;
    ushort* kb   = qb   + HB;
    ushort* vb   = kb   + HB;
    ushort* vt   = vb   + HB;                        // [BH][DH][NSEQ]
    ushort* woTh = vt   + HB;                        // [DIM][INNER]
    ushort* woTl = woTh + (size_t)DIM*INNER;
    ushort* wqTh = woTl + (size_t)DIM*INNER;         // [QKVN][DIM]
    ushort* wqTl = wqTh + (size_t)QKVN*DIM;
    ushort* xh   = wqTl + (size_t)QKVN*DIM;          // [NTOK][DIM]
    ushort* xl   = xh   + HB;
    // omh/oml reuse xh/xl (x consumed by kernel 1; om written by kernel 2)
    ushort* omh  = xh;
    ushort* oml  = xl;

    split_cvt_kernel<<<dim3(NTOK*DIM/1024), 256, 0, stream>>>(x, xh, xl);
    tconv_split_kernel<<<dim3(QKVN/32, DIM/32), 256, 0, stream>>>(w_qkv, wqTh, wqTl, DIM, QKVN);
    tconv_split_kernel<<<dim3(DIM/32, INNER/32), 256, 0, stream>>>(w_out, woTh, woTl, INNER, DIM);

    qkv_gemm_split<<<dim3(NTOK/128, QKVN/128), 256, 65536, stream>>>(
        wqTh, wqTl, xh, xl, b_qkv, rot, trans, qb, kb, vb);
    vtrans_kernel<<<dim3(NSEQ/64, BSZ*NH), 256, 0, stream>>>(vb, vt);
    attn_mfma_kernel<<<dim3(NSEQ/128, BSZ*NH), 256, 0, stream>>>(
        qb, kb, vt, rot, trans, omh, oml);
    out_gemm_split<<<dim3(NTOK/128, DIM/128), 256, 65536, stream>>>(
        woTh, woTl, omh, oml, b_out, out);
}

// Round 10
// 203.014 us; speedup vs baseline: 1.0478x; 1.0478x over previous
//
#include <hip/hip_runtime.h>
#include <math.h>

#define BSZ   8
#define NSEQ  1024
#define DIM   512
#define NH    8
#define DH    64
#define INNER 512
#define NTOK  (BSZ*NSEQ)     // 8192
#define QKVN  (3*INNER)      // 1536

typedef __bf16 bf16x8 __attribute__((ext_vector_type(8)));
typedef float  f32x4  __attribute__((ext_vector_type(4)));

// q pre-scale: softmax scale (DH^-0.5 = 0.125) folded with log2(e)
#define QSCL (0.125f * 1.44269504088896f)

static __device__ __forceinline__ ushort f2bf(float f) {
    union { float f; unsigned u; } v; v.f = f;
    unsigned r = (v.u + 0x7FFFu + ((v.u >> 16) & 1u)) >> 16;  // RNE
    return (ushort)r;
}
static __device__ __forceinline__ float bf2f(ushort u) {
    union { unsigned u; float f; } v; v.u = ((unsigned)u) << 16;
    return v.f;
}
static __device__ __forceinline__ void split2(float x, ushort& h, ushort& l) {
    h = f2bf(x);
    l = f2bf(x - bf2f(h));
}
// async global->LDS DMA, 16B per lane; LDS dest = wave-uniform base + lane*16
static __device__ __forceinline__ void async16(const void* g, void* l) {
    __builtin_amdgcn_global_load_lds(
        (const __attribute__((address_space(1))) unsigned int*)g,
        (__attribute__((address_space(3))) unsigned int*)l, 16, 0, 0);
}

// ---------------------------------------------------------------------------
// Elementwise fp32 -> bf16 hi/lo split (x)
// ---------------------------------------------------------------------------
__global__ __launch_bounds__(256) void split_cvt_kernel(
    const float* __restrict__ in, ushort* __restrict__ oh, ushort* __restrict__ ol)
{
    const int i = blockIdx.x * 256 + threadIdx.x;
    float4 v = ((const float4*)in)[i];
    ushort4 h, l;
    split2(v.x, h.x, l.x); split2(v.y, h.y, l.y);
    split2(v.z, h.z, l.z); split2(v.w, h.w, l.w);
    ((ushort4*)oh)[i] = h;
    ((ushort4*)ol)[i] = l;
}

// ---------------------------------------------------------------------------
// Transpose + split: in [K][F] fp32 row-major -> outh/outl [F][K] bf16
// ---------------------------------------------------------------------------
__global__ __launch_bounds__(256) void tconv_split_kernel(
    const float* __restrict__ in, ushort* __restrict__ outh,
    ushort* __restrict__ outl, int K, int F)
{
    __shared__ float tile[32][33];
    const int bx = blockIdx.x;           // F/32
    const int by = blockIdx.y;           // K/32
    const int lx = threadIdx.x & 31, ly = threadIdx.x >> 5;
#pragma unroll
    for (int u = 0; u < 4; u++) {
        const int k = by*32 + ly + u*8;
        tile[ly + u*8][lx] = in[(size_t)k*F + bx*32 + lx];
    }
    __syncthreads();
#pragma unroll
    for (int u = 0; u < 4; u++) {
        const int f = bx*32 + ly + u*8;
        ushort h, l;
        split2(tile[lx][ly + u*8], h, l);
        outh[(size_t)f*K + by*32 + lx] = h;
        outl[(size_t)f*K + by*32 + lx] = l;
    }
}

// ---------------------------------------------------------------------------
// V transpose: vb [BH][N][DH] bf16 -> vt [BH][DH][N] bf16. 64x64 tiles.
// ---------------------------------------------------------------------------
__global__ __launch_bounds__(256) void vtrans_kernel(
    const ushort* __restrict__ vb, ushort* __restrict__ vt)
{
    __shared__ ushort tile[64][72];
    const int nt = blockIdx.x;           // 16
    const int bh = blockIdx.y;           // 64
    const int tid = threadIdx.x;
    const ushort* src = vb + (size_t)bh*NSEQ*DH + (size_t)nt*64*DH;
    ushort* dst = vt + (size_t)bh*DH*NSEQ + nt*64;

#pragma unroll
    for (int u = 0; u < 2; u++) {
        const int idx = tid + u*256;         // uint4 index (512 total)
        const int row = idx >> 3;            // 64 rows, 8 uint4/row
        const int col = (idx & 7) * 8;
        *(uint4*)&tile[row][col] = *(const uint4*)(src + row*DH + col);
    }
    __syncthreads();
#pragma unroll
    for (int u = 0; u < 2; u++) {
        const int idx = tid + u*256;
        const int d   = idx >> 3;
        const int n0  = (idx & 7) * 8;
        ushort tmp[8];
#pragma unroll
        for (int i = 0; i < 8; i++) tmp[i] = tile[n0+i][d];
        *(uint4*)&dst[(size_t)d*NSEQ + n0] = *(uint4*)tmp;
    }
}

// ---------------------------------------------------------------------------
// Kernel 1: qkv^T split-bf16 MFMA GEMM, async-DMA fragment-ordered staging,
// fine-grained vmcnt pipeline (no full drain at the chunk barrier):
//   stage(ch+1); s_waitcnt vmcnt(8); s_barrier; compute(ch); lgkm(0); s_barrier
// vmcnt is in-order, so vmcnt(8) waits exactly for chunk-ch's 8 DMAs while
// chunk-ch+1's stay in flight behind the barrier.
// ---------------------------------------------------------------------------
__global__ __launch_bounds__(256) void qkv_gemm_split(
    const ushort* __restrict__ Agh, const ushort* __restrict__ Agl,
    const ushort* __restrict__ Bgh, const ushort* __restrict__ Bgl,
    const float* __restrict__ bias, const float* __restrict__ rot,
    const float* __restrict__ trans,
    ushort* __restrict__ qb, ushort* __restrict__ kb, ushort* __restrict__ vb)
{
    extern __shared__ __align__(16) char smem[];   // 65536 B

    const int tid  = threadIdx.x;
    const int lane = tid & 63;
    const int w    = tid >> 6;
    const int c    = lane & 15;
    const int quad = lane >> 4;
    const int wr   = w >> 1, wc = w & 1;
    const int tn   = blockIdx.x;   // token tile (64)
    const int tf   = blockIdx.y;   // feature tile (12)

    f32x4 acc[4][4] = {};

    const ushort* wp = (w == 0) ? Agh : (w == 1) ? Agl : (w == 2) ? Bgh : Bgl;
    const ushort* wbase = wp + (size_t)((w < 2 ? tf : tn)*128 + c)*DIM + quad*8;

    auto stage = [&](int k0, int buf) {
#pragma unroll
        for (int g = 0; g < 8; g++)
            async16(wbase + (size_t)g*16*DIM + k0,
                    smem + buf*32768 + (w*8 + g)*1024);
    };

    stage(0, 0);

    for (int ch = 0; ch < 16; ch++) {
        const int cur = ch & 1, nxt = cur ^ 1;
        if (ch < 15) {
            stage((ch+1)*32, nxt);
            // wait only chunk-ch's 8 DMAs (oldest); ch+1's 8 stay in flight
            __asm__ volatile("s_waitcnt vmcnt(8)\n\ts_barrier" ::: "memory");
        } else {
            __asm__ volatile("s_waitcnt vmcnt(0)\n\ts_barrier" ::: "memory");
        }

        const char* B = smem + cur*32768;
        bf16x8 fah[4], fal[4], fbh[4], fbl[4];
#pragma unroll
        for (int i = 0; i < 4; i++) {
            fah[i] = *(const bf16x8*)(B + ( 0 + wr*4 + i)*1024 + lane*16);
            fal[i] = *(const bf16x8*)(B + ( 8 + wr*4 + i)*1024 + lane*16);
        }
#pragma unroll
        for (int j = 0; j < 4; j++) {
            fbh[j] = *(const bf16x8*)(B + (16 + wc*4 + j)*1024 + lane*16);
            fbl[j] = *(const bf16x8*)(B + (24 + wc*4 + j)*1024 + lane*16);
        }
#pragma unroll
        for (int i = 0; i < 4; i++)
#pragma unroll
            for (int j = 0; j < 4; j++) {
                acc[i][j] = __builtin_amdgcn_mfma_f32_16x16x32_bf16(
                    fah[i], fbh[j], acc[i][j], 0, 0, 0);
                acc[i][j] = __builtin_amdgcn_mfma_f32_16x16x32_bf16(
                    fah[i], fbl[j], acc[i][j], 0, 0, 0);
                acc[i][j] = __builtin_amdgcn_mfma_f32_16x16x32_bf16(
                    fal[i], fbh[j], acc[i][j], 0, 0, 0);
            }
        // all LDS reads retired before the buffer can be overwritten next iter
        __asm__ volatile("s_waitcnt lgkmcnt(0)\n\ts_barrier" ::: "memory");
    }

    // epilogue: bias + SE(3) pose + scatter (verified mapping)
    const int sec = tf >> 2;          // 0=q 1=k 2=v (block-uniform)
    ushort* dstbuf = (sec == 0) ? qb : ((sec == 1) ? kb : vb);

#pragma unroll
    for (int j = 0; j < 4; j++) {
        const int tc = tn*128 + wc*64 + j*16 + c;
        const int bb = tc >> 10, n = tc & 1023;
        const float* R = rot   + (size_t)(bb*NSEQ + n)*9;
        const float* T = trans + (size_t)(bb*NSEQ + n)*3;
        const float R0=R[0],R1=R[1],R2=R[2],R3=R[3],R4=R[4],R5=R[5],R6=R[6],R7=R[7],R8=R[8];
        const float T0=T[0],T1=T[1],T2=T[2];
        float ti0 = 0.f, ti1 = 0.f, ti2 = 0.f;
        if (sec == 0) {
            ti0 = -(R0*T0 + R3*T1 + R6*T2);
            ti1 = -(R1*T0 + R4*T1 + R7*T2);
            ti2 = -(R2*T0 + R5*T1 + R8*T2);
        }
#pragma unroll
        for (int i = 0; i < 4; i++) {
            const int fr = tf*128 + wr*64 + i*16 + quad*4;
            const int fl = fr & 511;
            const int h  = fl >> 6, d = fl & 63;
            float4 bv = *(const float4*)(bias + fr);
            const float g0 = acc[i][j][0] + bv.x;
            const float g1 = acc[i][j][1] + bv.y;
            const float g2 = acc[i][j][2] + bv.z;
            const float g3 = acc[i][j][3] + bv.w;
            float o0, o1, o2, o3;
            if (sec == 0) {
                o0 = (R0*g0 + R1*g1 + R2*g2) * QSCL;
                o1 = (R3*g0 + R4*g1 + R5*g2) * QSCL;
                o2 = (R6*g0 + R7*g1 + R8*g2) * QSCL;
                o3 = (ti0*g0 + ti1*g1 + ti2*g2 + g3) * QSCL;
            } else {
                o0 = R0*g0 + R1*g1 + R2*g2 + T0*g3;
                o1 = R3*g0 + R4*g1 + R5*g2 + T1*g3;
                o2 = R6*g0 + R7*g1 + R8*g2 + T2*g3;
                o3 = g3;
            }
            ushort4 ov = { f2bf(o0), f2bf(o1), f2bf(o2), f2bf(o3) };
            *(ushort4*)(dstbuf + ((size_t)((bb*NH + h)*NSEQ + n))*DH + d) = ov;
        }
    }
}

// ---------------------------------------------------------------------------
// Kernel 2: async-pipelined MFMA flash attention (R8, unchanged).
// ---------------------------------------------------------------------------
__global__ __launch_bounds__(256) void attn_mfma_kernel(
    const ushort* __restrict__ qb, const ushort* __restrict__ kb,
    const ushort* __restrict__ vt, const float* __restrict__ rot,
    const float* __restrict__ trans,
    ushort* __restrict__ omh, ushort* __restrict__ oml)
{
    __shared__ __align__(16) char smem[51200];

    const int tid  = threadIdx.x;
    const int lane = tid & 63;
    const int w    = tid >> 6;
    const int c    = lane & 15;
    const int quad = lane >> 4;

    const int qt = blockIdx.x;      // 0..7 (128 q rows)
    const int bh = blockIdx.y;      // 0..63
    const int bb = bh >> 3, h = bh & 7;

    const ushort* Q = qb + (size_t)bh * NSEQ * DH;
    const ushort* K = kb + (size_t)bh * NSEQ * DH;
    const ushort* V = vt + (size_t)bh * DH * NSEQ;   // [DH][NSEQ]

    bf16x8 qf[2][2];
#pragma unroll
    for (int m = 0; m < 2; m++) {
        const ushort* qrow = Q + (size_t)(qt*128 + w*32 + m*16 + c)*DH + quad*8;
        qf[m][0] = *(const bf16x8*)(qrow);
        qf[m][1] = *(const bf16x8*)(qrow + 32);
    }

    f32x4 Oacc[2][4] = {};
    float lsum[2][4] = {};

    auto stage = [&](int kt, int buf) {
#pragma unroll
        for (int u = 0; u < 2; u++) {            // K segs
            const int seg = w + u*4;             // 0..7
            const int nt = seg >> 1, hh = seg & 1;
            const ushort* g = K + (size_t)(kt*64 + nt*16 + c)*DH + hh*32 + quad*8;
            async16(g, smem + buf*16384 + seg*1024);
        }
#pragma unroll
        for (int u = 0; u < 2; u++) {            // V segs
            const int s2 = w + u*4;              // 0..7
            const int nt = s2 >> 1, kc = s2 & 1;
            const ushort* g = V + (size_t)(nt*16 + c)*NSEQ + kt*64 + kc*32 + quad*8;
            async16(g, smem + buf*16384 + 8192 + s2*1024);
        }
    };

    stage(0, 0);
    __syncthreads();

    for (int kt = 0; kt < 16; kt++) {
        const int cur = kt & 1, nxt = cur ^ 1;
        if (kt < 15) stage(kt+1, nxt);

        const char* Kb = smem + cur*16384;
        const char* Vb = smem + cur*16384 + 8192;

        f32x4 s[2][4];
#pragma unroll
        for (int nt = 0; nt < 4; nt++) {
            bf16x8 k0 = *(const bf16x8*)(Kb + (nt*2+0)*1024 + lane*16);
            bf16x8 k1 = *(const bf16x8*)(Kb + (nt*2+1)*1024 + lane*16);
#pragma unroll
            for (int m = 0; m < 2; m++) {
                f32x4 a = {0.f, 0.f, 0.f, 0.f};
                a = __builtin_amdgcn_mfma_f32_16x16x32_bf16(qf[m][0], k0, a, 0, 0, 0);
                a = __builtin_amdgcn_mfma_f32_16x16x32_bf16(qf[m][1], k1, a, 0, 0, 0);
                s[m][nt] = a;
            }
        }

#pragma unroll
        for (int m = 0; m < 2; m++) {
            ushort (*Psw)[72] = (ushort (*)[72])(smem + 32768 + (w*2+m)*2304);
#pragma unroll
            for (int nt = 0; nt < 4; nt++)
#pragma unroll
                for (int r = 0; r < 4; r++) {
                    const float p = exp2f(s[m][nt][r]);
                    lsum[m][r] += p;
                    Psw[quad*4 + r][nt*16 + c] = (ushort)__builtin_bit_cast(
                        unsigned short, (__bf16)p);
                }
        }
        __asm__ volatile("s_waitcnt lgkmcnt(0)" ::: "memory");

#pragma unroll
        for (int kc = 0; kc < 2; kc++) {
            bf16x8 vfr[4];
#pragma unroll
            for (int nt = 0; nt < 4; nt++)
                vfr[nt] = *(const bf16x8*)(Vb + (nt*2+kc)*1024 + lane*16);
#pragma unroll
            for (int m = 0; m < 2; m++) {
                ushort (*Psw)[72] = (ushort (*)[72])(smem + 32768 + (w*2+m)*2304);
                bf16x8 a = *(const bf16x8*)&Psw[c][kc*32 + quad*8];
#pragma unroll
                for (int nt = 0; nt < 4; nt++)
                    Oacc[m][nt] = __builtin_amdgcn_mfma_f32_16x16x32_bf16(
                        a, vfr[nt], Oacc[m][nt], 0, 0, 0);
            }
        }
        __syncthreads();
    }

#pragma unroll
    for (int mk = 1; mk < 16; mk <<= 1)
#pragma unroll
        for (int m = 0; m < 2; m++)
#pragma unroll
            for (int r = 0; r < 4; r++)
                lsum[m][r] += __shfl_xor(lsum[m][r], mk);

    float (*Osh)[68] = (float (*)[68])smem;   // [128][68]
    {
        float inv[2][4];
#pragma unroll
        for (int m = 0; m < 2; m++)
#pragma unroll
            for (int r = 0; r < 4; r++) inv[m][r] = 1.f / lsum[m][r];
#pragma unroll
        for (int m = 0; m < 2; m++)
#pragma unroll
            for (int nt = 0; nt < 4; nt++)
#pragma unroll
                for (int r = 0; r < 4; r++)
                    Osh[w*32 + m*16 + quad*4 + r][nt*16 + c] =
                        Oacc[m][nt][r] * inv[m][r];
    }
    __syncthreads();

#pragma unroll
    for (int u = 0; u < 8; u++) {
        const int t   = tid + u*256;       // 0..2047
        const int row = t >> 4;            // 0..127
        const int g   = t & 15;
        const int n   = qt*128 + row;
        const float o0 = Osh[row][g*4+0], o1 = Osh[row][g*4+1];
        const float o2 = Osh[row][g*4+2], o3 = Osh[row][g*4+3];
        const float* R = rot   + (size_t)(bb*NSEQ + n)*9;
        const float* T = trans + (size_t)(bb*NSEQ + n)*3;
        const float ti0 = -(R[0]*T[0] + R[3]*T[1] + R[6]*T[2]);
        const float ti1 = -(R[1]*T[0] + R[4]*T[1] + R[7]*T[2]);
        const float ti2 = -(R[2]*T[0] + R[5]*T[1] + R[8]*T[2]);
        const float p0 = R[0]*o0 + R[3]*o1 + R[6]*o2 + ti0*o3;
        const float p1 = R[1]*o0 + R[4]*o1 + R[7]*o2 + ti1*o3;
        const float p2 = R[2]*o0 + R[5]*o1 + R[8]*o2 + ti2*o3;
        const float p3 = o3;
        ushort4 hv, lv;
        split2(p0, hv.x, lv.x); split2(p1, hv.y, lv.y);
        split2(p2, hv.z, lv.z); split2(p3, hv.w, lv.w);
        const size_t idx = (size_t)(bb*NSEQ + n)*INNER + h*DH + g*4;
        *(ushort4*)(omh + idx) = hv;
        *(ushort4*)(oml + idx) = lv;
    }
}

// ---------------------------------------------------------------------------
// Kernel 3: out^T split-bf16 MFMA GEMM, same fine-grained vmcnt pipeline.
// ---------------------------------------------------------------------------
__global__ __launch_bounds__(256) void out_gemm_split(
    const ushort* __restrict__ Agh, const ushort* __restrict__ Agl,
    const ushort* __restrict__ Bgh, const ushort* __restrict__ Bgl,
    const float* __restrict__ bias, float* __restrict__ out)
{
    extern __shared__ __align__(16) char smem[];   // 65536 B

    const int tid  = threadIdx.x;
    const int lane = tid & 63;
    const int w    = tid >> 6;
    const int c    = lane & 15;
    const int quad = lane >> 4;
    const int wr   = w >> 1, wc = w & 1;
    const int tn   = blockIdx.x;   // token tile (64)
    const int tf   = blockIdx.y;   // feature tile (4)

    f32x4 acc[4][4] = {};

    const ushort* wp = (w == 0) ? Agh : (w == 1) ? Agl : (w == 2) ? Bgh : Bgl;
    const ushort* wbase = wp + (size_t)((w < 2 ? tf : tn)*128 + c)*INNER + quad*8;

    auto stage = [&](int k0, int buf) {
#pragma unroll
        for (int g = 0; g < 8; g++)
            async16(wbase + (size_t)g*16*INNER + k0,
                    smem + buf*32768 + (w*8 + g)*1024);
    };

    stage(0, 0);

    for (int ch = 0; ch < 16; ch++) {
        const int cur = ch & 1, nxt = cur ^ 1;
        if (ch < 15) {
            stage((ch+1)*32, nxt);
            __asm__ volatile("s_waitcnt vmcnt(8)\n\ts_barrier" ::: "memory");
        } else {
            __asm__ volatile("s_waitcnt vmcnt(0)\n\ts_barrier" ::: "memory");
        }

        const char* B = smem + cur*32768;
        bf16x8 fah[4], fal[4], fbh[4], fbl[4];
#pragma unroll
        for (int i = 0; i < 4; i++) {
            fah[i] = *(const bf16x8*)(B + ( 0 + wr*4 + i)*1024 + lane*16);
            fal[i] = *(const bf16x8*)(B + ( 8 + wr*4 + i)*1024 + lane*16);
        }
#pragma unroll
        for (int j = 0; j < 4; j++) {
            fbh[j] = *(const bf16x8*)(B + (16 + wc*4 + j)*1024 + lane*16);
            fbl[j] = *(const bf16x8*)(B + (24 + wc*4 + j)*1024 + lane*16);
        }
#pragma unroll
        for (int i = 0; i < 4; i++)
#pragma unroll
            for (int j = 0; j < 4; j++) {
                acc[i][j] = __builtin_amdgcn_mfma_f32_16x16x32_bf16(
                    fah[i], fbh[j], acc[i][j], 0, 0, 0);
                acc[i][j] = __builtin_amdgcn_mfma_f32_16x16x32_bf16(
                    fah[i], fbl[j], acc[i][j], 0, 0, 0);
                acc[i][j] = __builtin_amdgcn_mfma_f32_16x16x32_bf16(
                    fal[i], fbh[j], acc[i][j], 0, 0, 0);
            }
        __asm__ volatile("s_waitcnt lgkmcnt(0)\n\ts_barrier" ::: "memory");
    }

#pragma unroll
    for (int j = 0; j < 4; j++) {
        const int tc = tn*128 + wc*64 + j*16 + c;
#pragma unroll
        for (int i = 0; i < 4; i++) {
            const int fr = tf*128 + wr*64 + i*16 + quad*4;
            float4 bv = *(const float4*)(bias + fr);
            float4 ov = { acc[i][j][0] + bv.x, acc[i][j][1] + bv.y,
                          acc[i][j][2] + bv.z, acc[i][j][3] + bv.w };
            *(float4*)(out + (size_t)tc*DIM + fr) = ov;
        }
    }
}

extern "C" void kernel_launch(void* const* d_in, const int* in_sizes, int n_in,
                              void* d_out, int out_size, void* d_ws, size_t ws_size,
                              hipStream_t stream) {
    (void)in_sizes; (void)n_in; (void)out_size; (void)ws_size;
    const float* x     = (const float*)d_in[0];
    const float* rot   = (const float*)d_in[1];
    const float* trans = (const float*)d_in[2];
    const float* w_qkv = (const float*)d_in[3];
    const float* b_qkv = (const float*)d_in[4];
    const float* w_out = (const float*)d_in[5];
    const float* b_out = (const float*)d_in[6];
    float* out = (float*)d_out;

    const size_t HB = (size_t)BSZ*NH*NSEQ*DH;        // 4,194,304 elements
    ushort* qb   = (ushort*)d_ws;
    ushort* kb   = qb   + HB;
    ushort* vb   = kb   + HB;
    ushort* vt   = vb   + HB;                        // [BH][DH][NSEQ]
    ushort* woTh = vt   + HB;                        // [DIM][INNER]
    ushort* woTl = woTh + (size_t)DIM*INNER;
    ushort* wqTh = woTl + (size_t)DIM*INNER;         // [QKVN][DIM]
    ushort* wqTl = wqTh + (size_t)QKVN*DIM;
    ushort* xh   = wqTl + (size_t)QKVN*DIM;          // [NTOK][DIM]
    ushort* xl   = xh   + HB;
    // omh/oml reuse xh/xl (x consumed by kernel 1; om written by kernel 2)
    ushort* omh  = xh;
    ushort* oml  = xl;

    split_cvt_kernel<<<dim3(NTOK*DIM/1024), 256, 0, stream>>>(x, xh, xl);
    tconv_split_kernel<<<dim3(QKVN/32, DIM/32), 256, 0, stream>>>(w_qkv, wqTh, wqTl, DIM, QKVN);
    tconv_split_kernel<<<dim3(DIM/32, INNER/32), 256, 0, stream>>>(w_out, woTh, woTl, INNER, DIM);

    qkv_gemm_split<<<dim3(NTOK/128, QKVN/128), 256, 65536, stream>>>(
        wqTh, wqTl, xh, xl, b_qkv, rot, trans, qb, kb, vb);
    vtrans_kernel<<<dim3(NSEQ/64, BSZ*NH), 256, 0, stream>>>(vb, vt);
    attn_mfma_kernel<<<dim3(NSEQ/128, BSZ*NH), 256, 0, stream>>>(
        qb, kb, vt, rot, trans, omh, oml);
    out_gemm_split<<<dim3(NTOK/128, DIM/128), 256, 65536, stream>>>(
        woTh, woTl, omh, oml, b_out, out);
}

// Round 11
// 184.995 us; speedup vs baseline: 1.1498x; 1.0974x over previous
//
#include <hip/hip_runtime.h>
#include <math.h>

#define BSZ   8
#define NSEQ  1024
#define DIM   512
#define NH    8
#define DH    64
#define INNER 512
#define NTOK  (BSZ*NSEQ)     // 8192
#define QKVN  (3*INNER)      // 1536

typedef __bf16 bf16x8 __attribute__((ext_vector_type(8)));
typedef float  f32x4  __attribute__((ext_vector_type(4)));

// q pre-scale: softmax scale (DH^-0.5 = 0.125) folded with log2(e)
#define QSCL (0.125f * 1.44269504088896f)

static __device__ __forceinline__ ushort f2bf(float f) {
    union { float f; unsigned u; } v; v.f = f;
    unsigned r = (v.u + 0x7FFFu + ((v.u >> 16) & 1u)) >> 16;  // RNE
    return (ushort)r;
}
static __device__ __forceinline__ float bf2f(ushort u) {
    union { unsigned u; float f; } v; v.u = ((unsigned)u) << 16;
    return v.f;
}
static __device__ __forceinline__ void split2(float x, ushort& h, ushort& l) {
    h = f2bf(x);
    l = f2bf(x - bf2f(h));
}
// async global->LDS DMA, 16B per lane; LDS dest = wave-uniform base + lane*16
static __device__ __forceinline__ void async16(const void* g, void* l) {
    __builtin_amdgcn_global_load_lds(
        (const __attribute__((address_space(1))) unsigned int*)g,
        (__attribute__((address_space(3))) unsigned int*)l, 16, 0, 0);
}

// ---------------------------------------------------------------------------
// Elementwise fp32 -> bf16 hi/lo split (x)
// ---------------------------------------------------------------------------
__global__ __launch_bounds__(256) void split_cvt_kernel(
    const float* __restrict__ in, ushort* __restrict__ oh, ushort* __restrict__ ol)
{
    const int i = blockIdx.x * 256 + threadIdx.x;
    float4 v = ((const float4*)in)[i];
    ushort4 h, l;
    split2(v.x, h.x, l.x); split2(v.y, h.y, l.y);
    split2(v.z, h.z, l.z); split2(v.w, h.w, l.w);
    ((ushort4*)oh)[i] = h;
    ((ushort4*)ol)[i] = l;
}

// ---------------------------------------------------------------------------
// Transpose + convert: in [K][F] fp32 row-major -> out [F][K] bf16 (hi only)
// ---------------------------------------------------------------------------
__global__ __launch_bounds__(256) void tconv_kernel(
    const float* __restrict__ in, ushort* __restrict__ outh, int K, int F)
{
    __shared__ float tile[32][33];
    const int bx = blockIdx.x;           // F/32
    const int by = blockIdx.y;           // K/32
    const int lx = threadIdx.x & 31, ly = threadIdx.x >> 5;
#pragma unroll
    for (int u = 0; u < 4; u++) {
        const int k = by*32 + ly + u*8;
        tile[ly + u*8][lx] = in[(size_t)k*F + bx*32 + lx];
    }
    __syncthreads();
#pragma unroll
    for (int u = 0; u < 4; u++) {
        const int f = bx*32 + ly + u*8;
        outh[(size_t)f*K + by*32 + lx] = f2bf(tile[lx][ly + u*8]);
    }
}

// ---------------------------------------------------------------------------
// Kernel 1: qkv^T MFMA GEMM: C = w_bf16 * (xh + xl), 2 passes, 3 staged
// parts (Ah/Bh/Bl), BK=32, fine-grained vmcnt pipeline, LDS 48KB ->
// 3 blocks/CU. Epilogue: bias + SE(3) pose; q,k row-major; V written
// TRANSPOSED straight to vt (fuses the old vtrans kernel).
// ---------------------------------------------------------------------------
__global__ __launch_bounds__(256) void qkv_gemm_split(
    const ushort* __restrict__ Agh, const ushort* __restrict__ Bgh,
    const ushort* __restrict__ Bgl,
    const float* __restrict__ bias, const float* __restrict__ rot,
    const float* __restrict__ trans,
    ushort* __restrict__ qb, ushort* __restrict__ kb, ushort* __restrict__ vt)
{
    extern __shared__ __align__(16) char smem[];   // 49152 B

    const int tid  = threadIdx.x;
    const int lane = tid & 63;
    const int w    = tid >> 6;
    const int c    = lane & 15;
    const int quad = lane >> 4;
    const int wr   = w >> 1, wc = w & 1;
    const int tn   = blockIdx.x;   // token tile (64)
    const int tf   = blockIdx.y;   // feature tile (12)

    f32x4 acc[4][4] = {};

    // wave roles: 0 -> Ah, 1 -> Bh, 2 -> Bl, 3 -> idle (issue-only staging)
    const ushort* wp = (w == 0) ? Agh : (w == 1) ? Bgh : Bgl;
    const ushort* wbase = wp + (size_t)((w == 0 ? tf : tn)*128 + c)*DIM + quad*8;
    const int lbase = w * 8192;    // A at 0, Bh at 8192, Bl at 16384

    auto stage = [&](int k0, int buf) {
        if (w < 3) {
#pragma unroll
            for (int g = 0; g < 8; g++)
                async16(wbase + (size_t)g*16*DIM + k0,
                        smem + buf*24576 + lbase + g*1024);
        }
    };

    stage(0, 0);

    for (int ch = 0; ch < 16; ch++) {
        const int cur = ch & 1, nxt = cur ^ 1;
        if (ch < 15) {
            stage((ch+1)*32, nxt);
            // wait only chunk-ch's 8 DMAs (oldest); ch+1's stay in flight
            __asm__ volatile("s_waitcnt vmcnt(8)\n\ts_barrier" ::: "memory");
        } else {
            __asm__ volatile("s_waitcnt vmcnt(0)\n\ts_barrier" ::: "memory");
        }

        const char* B = smem + cur*24576;
        bf16x8 fa[4], fbh[4], fbl[4];
#pragma unroll
        for (int i = 0; i < 4; i++)
            fa[i] = *(const bf16x8*)(B + (wr*4 + i)*1024 + lane*16);
#pragma unroll
        for (int j = 0; j < 4; j++) {
            fbh[j] = *(const bf16x8*)(B +  8192 + (wc*4 + j)*1024 + lane*16);
            fbl[j] = *(const bf16x8*)(B + 16384 + (wc*4 + j)*1024 + lane*16);
        }
#pragma unroll
        for (int i = 0; i < 4; i++)
#pragma unroll
            for (int j = 0; j < 4; j++) {
                acc[i][j] = __builtin_amdgcn_mfma_f32_16x16x32_bf16(
                    fa[i], fbh[j], acc[i][j], 0, 0, 0);
                acc[i][j] = __builtin_amdgcn_mfma_f32_16x16x32_bf16(
                    fa[i], fbl[j], acc[i][j], 0, 0, 0);
            }
        __asm__ volatile("s_waitcnt lgkmcnt(0)\n\ts_barrier" ::: "memory");
    }

    // epilogue: bias + SE(3) pose + scatter (verified mapping)
    const int sec = tf >> 2;          // 0=q 1=k 2=v (block-uniform)

#pragma unroll
    for (int j = 0; j < 4; j++) {
        const int tc = tn*128 + wc*64 + j*16 + c;
        const int bb = tc >> 10, n = tc & 1023;
        const float* R = rot   + (size_t)(bb*NSEQ + n)*9;
        const float* T = trans + (size_t)(bb*NSEQ + n)*3;
        const float R0=R[0],R1=R[1],R2=R[2],R3=R[3],R4=R[4],R5=R[5],R6=R[6],R7=R[7],R8=R[8];
        const float T0=T[0],T1=T[1],T2=T[2];
        float ti0 = 0.f, ti1 = 0.f, ti2 = 0.f;
        if (sec == 0) {
            ti0 = -(R0*T0 + R3*T1 + R6*T2);
            ti1 = -(R1*T0 + R4*T1 + R7*T2);
            ti2 = -(R2*T0 + R5*T1 + R8*T2);
        }
#pragma unroll
        for (int i = 0; i < 4; i++) {
            const int fr = tf*128 + wr*64 + i*16 + quad*4;
            const int fl = fr & 511;
            const int h  = fl >> 6, d = fl & 63;
            float4 bv = *(const float4*)(bias + fr);
            const float g0 = acc[i][j][0] + bv.x;
            const float g1 = acc[i][j][1] + bv.y;
            const float g2 = acc[i][j][2] + bv.z;
            const float g3 = acc[i][j][3] + bv.w;
            if (sec == 0) {
                float o0 = (R0*g0 + R1*g1 + R2*g2) * QSCL;
                float o1 = (R3*g0 + R4*g1 + R5*g2) * QSCL;
                float o2 = (R6*g0 + R7*g1 + R8*g2) * QSCL;
                float o3 = (ti0*g0 + ti1*g1 + ti2*g2 + g3) * QSCL;
                ushort4 ov = { f2bf(o0), f2bf(o1), f2bf(o2), f2bf(o3) };
                *(ushort4*)(qb + ((size_t)((bb*NH + h)*NSEQ + n))*DH + d) = ov;
            } else {
                float o0 = R0*g0 + R1*g1 + R2*g2 + T0*g3;
                float o1 = R3*g0 + R4*g1 + R5*g2 + T1*g3;
                float o2 = R6*g0 + R7*g1 + R8*g2 + T2*g3;
                float o3 = g3;
                if (sec == 1) {
                    ushort4 ov = { f2bf(o0), f2bf(o1), f2bf(o2), f2bf(o3) };
                    *(ushort4*)(kb + ((size_t)((bb*NH + h)*NSEQ + n))*DH + d) = ov;
                } else {
                    // v: write TRANSPOSED -> vt[bh][d][n]
                    ushort* vtb = vt + ((size_t)(bb*NH + h)*DH + d)*NSEQ + n;
                    vtb[0*NSEQ] = f2bf(o0);
                    vtb[1*NSEQ] = f2bf(o1);
                    vtb[2*NSEQ] = f2bf(o2);
                    vtb[3*NSEQ] = f2bf(o3);
                }
            }
        }
    }
}

// ---------------------------------------------------------------------------
// Kernel 2: async-pipelined MFMA flash attention (R8, unchanged).
// ---------------------------------------------------------------------------
__global__ __launch_bounds__(256) void attn_mfma_kernel(
    const ushort* __restrict__ qb, const ushort* __restrict__ kb,
    const ushort* __restrict__ vt, const float* __restrict__ rot,
    const float* __restrict__ trans,
    ushort* __restrict__ omh, ushort* __restrict__ oml)
{
    __shared__ __align__(16) char smem[51200];

    const int tid  = threadIdx.x;
    const int lane = tid & 63;
    const int w    = tid >> 6;
    const int c    = lane & 15;
    const int quad = lane >> 4;

    const int qt = blockIdx.x;      // 0..7 (128 q rows)
    const int bh = blockIdx.y;      // 0..63
    const int bb = bh >> 3, h = bh & 7;

    const ushort* Q = qb + (size_t)bh * NSEQ * DH;
    const ushort* K = kb + (size_t)bh * NSEQ * DH;
    const ushort* V = vt + (size_t)bh * DH * NSEQ;   // [DH][NSEQ]

    bf16x8 qf[2][2];
#pragma unroll
    for (int m = 0; m < 2; m++) {
        const ushort* qrow = Q + (size_t)(qt*128 + w*32 + m*16 + c)*DH + quad*8;
        qf[m][0] = *(const bf16x8*)(qrow);
        qf[m][1] = *(const bf16x8*)(qrow + 32);
    }

    f32x4 Oacc[2][4] = {};
    float lsum[2][4] = {};

    auto stage = [&](int kt, int buf) {
#pragma unroll
        for (int u = 0; u < 2; u++) {            // K segs
            const int seg = w + u*4;             // 0..7
            const int nt = seg >> 1, hh = seg & 1;
            const ushort* g = K + (size_t)(kt*64 + nt*16 + c)*DH + hh*32 + quad*8;
            async16(g, smem + buf*16384 + seg*1024);
        }
#pragma unroll
        for (int u = 0; u < 2; u++) {            // V segs
            const int s2 = w + u*4;              // 0..7
            const int nt = s2 >> 1, kc = s2 & 1;
            const ushort* g = V + (size_t)(nt*16 + c)*NSEQ + kt*64 + kc*32 + quad*8;
            async16(g, smem + buf*16384 + 8192 + s2*1024);
        }
    };

    stage(0, 0);
    __syncthreads();

    for (int kt = 0; kt < 16; kt++) {
        const int cur = kt & 1, nxt = cur ^ 1;
        if (kt < 15) stage(kt+1, nxt);

        const char* Kb = smem + cur*16384;
        const char* Vb = smem + cur*16384 + 8192;

        f32x4 s[2][4];
#pragma unroll
        for (int nt = 0; nt < 4; nt++) {
            bf16x8 k0 = *(const bf16x8*)(Kb + (nt*2+0)*1024 + lane*16);
            bf16x8 k1 = *(const bf16x8*)(Kb + (nt*2+1)*1024 + lane*16);
#pragma unroll
            for (int m = 0; m < 2; m++) {
                f32x4 a = {0.f, 0.f, 0.f, 0.f};
                a = __builtin_amdgcn_mfma_f32_16x16x32_bf16(qf[m][0], k0, a, 0, 0, 0);
                a = __builtin_amdgcn_mfma_f32_16x16x32_bf16(qf[m][1], k1, a, 0, 0, 0);
                s[m][nt] = a;
            }
        }

#pragma unroll
        for (int m = 0; m < 2; m++) {
            ushort (*Psw)[72] = (ushort (*)[72])(smem + 32768 + (w*2+m)*2304);
#pragma unroll
            for (int nt = 0; nt < 4; nt++)
#pragma unroll
                for (int r = 0; r < 4; r++) {
                    const float p = exp2f(s[m][nt][r]);
                    lsum[m][r] += p;
                    Psw[quad*4 + r][nt*16 + c] = (ushort)__builtin_bit_cast(
                        unsigned short, (__bf16)p);
                }
        }
        __asm__ volatile("s_waitcnt lgkmcnt(0)" ::: "memory");

#pragma unroll
        for (int kc = 0; kc < 2; kc++) {
            bf16x8 vfr[4];
#pragma unroll
            for (int nt = 0; nt < 4; nt++)
                vfr[nt] = *(const bf16x8*)(Vb + (nt*2+kc)*1024 + lane*16);
#pragma unroll
            for (int m = 0; m < 2; m++) {
                ushort (*Psw)[72] = (ushort (*)[72])(smem + 32768 + (w*2+m)*2304);
                bf16x8 a = *(const bf16x8*)&Psw[c][kc*32 + quad*8];
#pragma unroll
                for (int nt = 0; nt < 4; nt++)
                    Oacc[m][nt] = __builtin_amdgcn_mfma_f32_16x16x32_bf16(
                        a, vfr[nt], Oacc[m][nt], 0, 0, 0);
            }
        }
        __syncthreads();
    }

#pragma unroll
    for (int mk = 1; mk < 16; mk <<= 1)
#pragma unroll
        for (int m = 0; m < 2; m++)
#pragma unroll
            for (int r = 0; r < 4; r++)
                lsum[m][r] += __shfl_xor(lsum[m][r], mk);

    float (*Osh)[68] = (float (*)[68])smem;   // [128][68]
    {
        float inv[2][4];
#pragma unroll
        for (int m = 0; m < 2; m++)
#pragma unroll
            for (int r = 0; r < 4; r++) inv[m][r] = 1.f / lsum[m][r];
#pragma unroll
        for (int m = 0; m < 2; m++)
#pragma unroll
            for (int nt = 0; nt < 4; nt++)
#pragma unroll
                for (int r = 0; r < 4; r++)
                    Osh[w*32 + m*16 + quad*4 + r][nt*16 + c] =
                        Oacc[m][nt][r] * inv[m][r];
    }
    __syncthreads();

#pragma unroll
    for (int u = 0; u < 8; u++) {
        const int t   = tid + u*256;       // 0..2047
        const int row = t >> 4;            // 0..127
        const int g   = t & 15;
        const int n   = qt*128 + row;
        const float o0 = Osh[row][g*4+0], o1 = Osh[row][g*4+1];
        const float o2 = Osh[row][g*4+2], o3 = Osh[row][g*4+3];
        const float* R = rot   + (size_t)(bb*NSEQ + n)*9;
        const float* T = trans + (size_t)(bb*NSEQ + n)*3;
        const float ti0 = -(R[0]*T[0] + R[3]*T[1] + R[6]*T[2]);
        const float ti1 = -(R[1]*T[0] + R[4]*T[1] + R[7]*T[2]);
        const float ti2 = -(R[2]*T[0] + R[5]*T[1] + R[8]*T[2]);
        const float p0 = R[0]*o0 + R[3]*o1 + R[6]*o2 + ti0*o3;
        const float p1 = R[1]*o0 + R[4]*o1 + R[7]*o2 + ti1*o3;
        const float p2 = R[2]*o0 + R[5]*o1 + R[8]*o2 + ti2*o3;
        const float p3 = o3;
        ushort4 hv, lv;
        split2(p0, hv.x, lv.x); split2(p1, hv.y, lv.y);
        split2(p2, hv.z, lv.z); split2(p3, hv.w, lv.w);
        const size_t idx = (size_t)(bb*NSEQ + n)*INNER + h*DH + g*4;
        *(ushort4*)(omh + idx) = hv;
        *(ushort4*)(oml + idx) = lv;
    }
}

// ---------------------------------------------------------------------------
// Kernel 3: out^T MFMA GEMM: C = woT_bf16 * (omh + oml), 2 passes, 3 staged
// parts, same pipeline as kernel 1. Epilogue: + bias, fp32 store.
// ---------------------------------------------------------------------------
__global__ __launch_bounds__(256) void out_gemm_split(
    const ushort* __restrict__ Agh, const ushort* __restrict__ Bgh,
    const ushort* __restrict__ Bgl,
    const float* __restrict__ bias, float* __restrict__ out)
{
    extern __shared__ __align__(16) char smem[];   // 49152 B

    const int tid  = threadIdx.x;
    const int lane = tid & 63;
    const int w    = tid >> 6;
    const int c    = lane & 15;
    const int quad = lane >> 4;
    const int wr   = w >> 1, wc = w & 1;
    const int tn   = blockIdx.x;   // token tile (64)
    const int tf   = blockIdx.y;   // feature tile (4)

    f32x4 acc[4][4] = {};

    const ushort* wp = (w == 0) ? Agh : (w == 1) ? Bgh : Bgl;
    const ushort* wbase = wp + (size_t)((w == 0 ? tf : tn)*128 + c)*INNER + quad*8;
    const int lbase = w * 8192;

    auto stage = [&](int k0, int buf) {
        if (w < 3) {
#pragma unroll
            for (int g = 0; g < 8; g++)
                async16(wbase + (size_t)g*16*INNER + k0,
                        smem + buf*24576 + lbase + g*1024);
        }
    };

    stage(0, 0);

    for (int ch = 0; ch < 16; ch++) {
        const int cur = ch & 1, nxt = cur ^ 1;
        if (ch < 15) {
            stage((ch+1)*32, nxt);
            __asm__ volatile("s_waitcnt vmcnt(8)\n\ts_barrier" ::: "memory");
        } else {
            __asm__ volatile("s_waitcnt vmcnt(0)\n\ts_barrier" ::: "memory");
        }

        const char* B = smem + cur*24576;
        bf16x8 fa[4], fbh[4], fbl[4];
#pragma unroll
        for (int i = 0; i < 4; i++)
            fa[i] = *(const bf16x8*)(B + (wr*4 + i)*1024 + lane*16);
#pragma unroll
        for (int j = 0; j < 4; j++) {
            fbh[j] = *(const bf16x8*)(B +  8192 + (wc*4 + j)*1024 + lane*16);
            fbl[j] = *(const bf16x8*)(B + 16384 + (wc*4 + j)*1024 + lane*16);
        }
#pragma unroll
        for (int i = 0; i < 4; i++)
#pragma unroll
            for (int j = 0; j < 4; j++) {
                acc[i][j] = __builtin_amdgcn_mfma_f32_16x16x32_bf16(
                    fa[i], fbh[j], acc[i][j], 0, 0, 0);
                acc[i][j] = __builtin_amdgcn_mfma_f32_16x16x32_bf16(
                    fa[i], fbl[j], acc[i][j], 0, 0, 0);
            }
        __asm__ volatile("s_waitcnt lgkmcnt(0)\n\ts_barrier" ::: "memory");
    }

#pragma unroll
    for (int j = 0; j < 4; j++) {
        const int tc = tn*128 + wc*64 + j*16 + c;
#pragma unroll
        for (int i = 0; i < 4; i++) {
            const int fr = tf*128 + wr*64 + i*16 + quad*4;
            float4 bv = *(const float4*)(bias + fr);
            float4 ov = { acc[i][j][0] + bv.x, acc[i][j][1] + bv.y,
                          acc[i][j][2] + bv.z, acc[i][j][3] + bv.w };
            *(float4*)(out + (size_t)tc*DIM + fr) = ov;
        }
    }
}

extern "C" void kernel_launch(void* const* d_in, const int* in_sizes, int n_in,
                              void* d_out, int out_size, void* d_ws, size_t ws_size,
                              hipStream_t stream) {
    (void)in_sizes; (void)n_in; (void)out_size; (void)ws_size;
    const float* x     = (const float*)d_in[0];
    const float* rot   = (const float*)d_in[1];
    const float* trans = (const float*)d_in[2];
    const float* w_qkv = (const float*)d_in[3];
    const float* b_qkv = (const float*)d_in[4];
    const float* w_out = (const float*)d_in[5];
    const float* b_out = (const float*)d_in[6];
    float* out = (float*)d_out;

    const size_t HB = (size_t)BSZ*NH*NSEQ*DH;        // 4,194,304 elements
    ushort* qb   = (ushort*)d_ws;
    ushort* kb   = qb   + HB;
    ushort* vt   = kb   + HB;                        // [BH][DH][NSEQ]
    ushort* woTh = vt   + HB;                        // [DIM][INNER]
    ushort* wqTh = woTh + (size_t)DIM*INNER;         // [QKVN][DIM]
    ushort* xh   = wqTh + (size_t)QKVN*DIM;          // [NTOK][DIM]
    ushort* xl   = xh   + HB;
    // omh/oml reuse xh/xl (x consumed by kernel 1; om written by kernel 2)
    ushort* omh  = xh;
    ushort* oml  = xl;

    split_cvt_kernel<<<dim3(NTOK*DIM/1024), 256, 0, stream>>>(x, xh, xl);
    tconv_kernel<<<dim3(QKVN/32, DIM/32), 256, 0, stream>>>(w_qkv, wqTh, DIM, QKVN);
    tconv_kernel<<<dim3(DIM/32, INNER/32), 256, 0, stream>>>(w_out, woTh, INNER, DIM);

    qkv_gemm_split<<<dim3(NTOK/128, QKVN/128), 256, 49152, stream>>>(
        wqTh, xh, xl, b_qkv, rot, trans, qb, kb, vt);
    attn_mfma_kernel<<<dim3(NSEQ/128, BSZ*NH), 256, 0, stream>>>(
        qb, kb, vt, rot, trans, omh, oml);
    out_gemm_split<<<dim3(NTOK/128, DIM/128), 256, 49152, stream>>>(
        woTh, omh, oml, b_out, out);
}

// Round 13
// 184.239 us; speedup vs baseline: 1.1545x; 1.0041x over previous
//
#include <hip/hip_runtime.h>
#include <math.h>

#define BSZ   8
#define NSEQ  1024
#define DIM   512
#define NH    8
#define DH    64
#define INNER 512
#define NTOK  (BSZ*NSEQ)     // 8192
#define QKVN  (3*INNER)      // 1536

typedef __bf16 bf16x8 __attribute__((ext_vector_type(8)));
typedef float  f32x4  __attribute__((ext_vector_type(4)));

// q pre-scale: softmax scale (DH^-0.5 = 0.125) folded with log2(e)
#define QSCL (0.125f * 1.44269504088896f)

static __device__ __forceinline__ ushort f2bf(float f) {
    union { float f; unsigned u; } v; v.f = f;
    unsigned r = (v.u + 0x7FFFu + ((v.u >> 16) & 1u)) >> 16;  // RNE
    return (ushort)r;
}
static __device__ __forceinline__ float bf2f(ushort u) {
    union { unsigned u; float f; } v; v.u = ((unsigned)u) << 16;
    return v.f;
}
static __device__ __forceinline__ void split2(float x, ushort& h, ushort& l) {
    h = f2bf(x);
    l = f2bf(x - bf2f(h));
}
// async global->LDS DMA, 16B per lane; LDS dest = wave-uniform base + lane*16
static __device__ __forceinline__ void async16(const void* g, void* l) {
    __builtin_amdgcn_global_load_lds(
        (const __attribute__((address_space(1))) unsigned int*)g,
        (__attribute__((address_space(3))) unsigned int*)l, 16, 0, 0);
}

// ---------------------------------------------------------------------------
// Elementwise fp32 -> bf16 hi/lo split (x)
// ---------------------------------------------------------------------------
__global__ __launch_bounds__(256) void split_cvt_kernel(
    const float* __restrict__ in, ushort* __restrict__ oh, ushort* __restrict__ ol)
{
    const int i = blockIdx.x * 256 + threadIdx.x;
    float4 v = ((const float4*)in)[i];
    ushort4 h, l;
    split2(v.x, h.x, l.x); split2(v.y, h.y, l.y);
    split2(v.z, h.z, l.z); split2(v.w, h.w, l.w);
    ((ushort4*)oh)[i] = h;
    ((ushort4*)ol)[i] = l;
}

// ---------------------------------------------------------------------------
// Transpose + convert: in [K][F] fp32 row-major -> out [F][K] bf16 (hi only)
// ---------------------------------------------------------------------------
__global__ __launch_bounds__(256) void tconv_kernel(
    const float* __restrict__ in, ushort* __restrict__ outh, int K, int F)
{
    __shared__ float tile[32][33];
    const int bx = blockIdx.x;           // F/32
    const int by = blockIdx.y;           // K/32
    const int lx = threadIdx.x & 31, ly = threadIdx.x >> 5;
#pragma unroll
    for (int u = 0; u < 4; u++) {
        const int k = by*32 + ly + u*8;
        tile[ly + u*8][lx] = in[(size_t)k*F + bx*32 + lx];
    }
    __syncthreads();
#pragma unroll
    for (int u = 0; u < 4; u++) {
        const int f = bx*32 + ly + u*8;
        outh[(size_t)f*K + by*32 + lx] = f2bf(tile[lx][ly + u*8]);
    }
}

// ---------------------------------------------------------------------------
// Kernel 1: qkv^T MFMA GEMM: C = w_bf16 * (xh + xl), 2 passes, 3 staged
// parts (Ah/Bh/Bl), BK=32, fine-grained vmcnt pipeline (R11, proven).
// Epilogue: bias + SE(3) pose; q,k row-major; V written transposed to vt.
// ---------------------------------------------------------------------------
__global__ __launch_bounds__(256) void qkv_gemm_split(
    const ushort* __restrict__ Agh, const ushort* __restrict__ Bgh,
    const ushort* __restrict__ Bgl,
    const float* __restrict__ bias, const float* __restrict__ rot,
    const float* __restrict__ trans,
    ushort* __restrict__ qb, ushort* __restrict__ kb, ushort* __restrict__ vt)
{
    extern __shared__ __align__(16) char smem[];   // 49152 B

    const int tid  = threadIdx.x;
    const int lane = tid & 63;
    const int w    = tid >> 6;
    const int c    = lane & 15;
    const int quad = lane >> 4;
    const int wr   = w >> 1, wc = w & 1;
    const int tn   = blockIdx.x;   // token tile (64)
    const int tf   = blockIdx.y;   // feature tile (12)

    f32x4 acc[4][4] = {};

    // wave roles: 0 -> Ah, 1 -> Bh, 2 -> Bl, 3 -> idle (issue-only staging)
    const ushort* wp = (w == 0) ? Agh : (w == 1) ? Bgh : Bgl;
    const ushort* wbase = wp + (size_t)((w == 0 ? tf : tn)*128 + c)*DIM + quad*8;
    const int lbase = w * 8192;    // A at 0, Bh at 8192, Bl at 16384

    auto stage = [&](int k0, int buf) {
        if (w < 3) {
#pragma unroll
            for (int g = 0; g < 8; g++)
                async16(wbase + (size_t)g*16*DIM + k0,
                        smem + buf*24576 + lbase + g*1024);
        }
    };

    stage(0, 0);

    for (int ch = 0; ch < 16; ch++) {
        const int cur = ch & 1, nxt = cur ^ 1;
        if (ch < 15) {
            stage((ch+1)*32, nxt);
            // wait only chunk-ch's 8 DMAs (oldest); ch+1's stay in flight
            __asm__ volatile("s_waitcnt vmcnt(8)\n\ts_barrier" ::: "memory");
        } else {
            __asm__ volatile("s_waitcnt vmcnt(0)\n\ts_barrier" ::: "memory");
        }

        const char* B = smem + cur*24576;
        bf16x8 fa[4], fbh[4], fbl[4];
#pragma unroll
        for (int i = 0; i < 4; i++)
            fa[i] = *(const bf16x8*)(B + (wr*4 + i)*1024 + lane*16);
#pragma unroll
        for (int j = 0; j < 4; j++) {
            fbh[j] = *(const bf16x8*)(B +  8192 + (wc*4 + j)*1024 + lane*16);
            fbl[j] = *(const bf16x8*)(B + 16384 + (wc*4 + j)*1024 + lane*16);
        }
#pragma unroll
        for (int i = 0; i < 4; i++)
#pragma unroll
            for (int j = 0; j < 4; j++) {
                acc[i][j] = __builtin_amdgcn_mfma_f32_16x16x32_bf16(
                    fa[i], fbh[j], acc[i][j], 0, 0, 0);
                acc[i][j] = __builtin_amdgcn_mfma_f32_16x16x32_bf16(
                    fa[i], fbl[j], acc[i][j], 0, 0, 0);
            }
        __asm__ volatile("s_waitcnt lgkmcnt(0)\n\ts_barrier" ::: "memory");
    }

    // epilogue: bias + SE(3) pose + scatter (verified mapping)
    const int sec = tf >> 2;          // 0=q 1=k 2=v (block-uniform)

#pragma unroll
    for (int j = 0; j < 4; j++) {
        const int tc = tn*128 + wc*64 + j*16 + c;
        const int bb = tc >> 10, n = tc & 1023;
        const float* R = rot   + (size_t)(bb*NSEQ + n)*9;
        const float* T = trans + (size_t)(bb*NSEQ + n)*3;
        const float R0=R[0],R1=R[1],R2=R[2],R3=R[3],R4=R[4],R5=R[5],R6=R[6],R7=R[7],R8=R[8];
        const float T0=T[0],T1=T[1],T2=T[2];
        float ti0 = 0.f, ti1 = 0.f, ti2 = 0.f;
        if (sec == 0) {
            ti0 = -(R0*T0 + R3*T1 + R6*T2);
            ti1 = -(R1*T0 + R4*T1 + R7*T2);
            ti2 = -(R2*T0 + R5*T1 + R8*T2);
        }
#pragma unroll
        for (int i = 0; i < 4; i++) {
            const int fr = tf*128 + wr*64 + i*16 + quad*4;
            const int fl = fr & 511;
            const int h  = fl >> 6, d = fl & 63;
            float4 bv = *(const float4*)(bias + fr);
            const float g0 = acc[i][j][0] + bv.x;
            const float g1 = acc[i][j][1] + bv.y;
            const float g2 = acc[i][j][2] + bv.z;
            const float g3 = acc[i][j][3] + bv.w;
            if (sec == 0) {
                float o0 = (R0*g0 + R1*g1 + R2*g2) * QSCL;
                float o1 = (R3*g0 + R4*g1 + R5*g2) * QSCL;
                float o2 = (R6*g0 + R7*g1 + R8*g2) * QSCL;
                float o3 = (ti0*g0 + ti1*g1 + ti2*g2 + g3) * QSCL;
                ushort4 ov = { f2bf(o0), f2bf(o1), f2bf(o2), f2bf(o3) };
                *(ushort4*)(qb + ((size_t)((bb*NH + h)*NSEQ + n))*DH + d) = ov;
            } else {
                float o0 = R0*g0 + R1*g1 + R2*g2 + T0*g3;
                float o1 = R3*g0 + R4*g1 + R5*g2 + T1*g3;
                float o2 = R6*g0 + R7*g1 + R8*g2 + T2*g3;
                float o3 = g3;
                if (sec == 1) {
                    ushort4 ov = { f2bf(o0), f2bf(o1), f2bf(o2), f2bf(o3) };
                    *(ushort4*)(kb + ((size_t)((bb*NH + h)*NSEQ + n))*DH + d) = ov;
                } else {
                    // v: write TRANSPOSED -> vt[bh][d][n]
                    ushort* vtb = vt + ((size_t)(bb*NH + h)*DH + d)*NSEQ + n;
                    vtb[0*NSEQ] = f2bf(o0);
                    vtb[1*NSEQ] = f2bf(o1);
                    vtb[2*NSEQ] = f2bf(o2);
                    vtb[3*NSEQ] = f2bf(o3);
                }
            }
        }
    }
}

// ---------------------------------------------------------------------------
// Kernel 2: async-pipelined MFMA flash attention with fine-grained vmcnt
// (R8 structure + the R10 vmcnt(N) barrier transform):
//   stage(kt+1); vmcnt(4); s_barrier; compute; lgkmcnt(0); s_barrier
// kt+1's 4 DMAs stay in flight through the whole body instead of being
// drained by __syncthreads' implicit vmcnt(0).
// ---------------------------------------------------------------------------
__global__ __launch_bounds__(256) void attn_mfma_kernel(
    const ushort* __restrict__ qb, const ushort* __restrict__ kb,
    const ushort* __restrict__ vt, const float* __restrict__ rot,
    const float* __restrict__ trans,
    ushort* __restrict__ omh, ushort* __restrict__ oml)
{
    __shared__ __align__(16) char smem[51200];

    const int tid  = threadIdx.x;
    const int lane = tid & 63;
    const int w    = tid >> 6;
    const int c    = lane & 15;
    const int quad = lane >> 4;

    const int qt = blockIdx.x;      // 0..7 (128 q rows)
    const int bh = blockIdx.y;      // 0..63
    const int bb = bh >> 3, h = bh & 7;

    const ushort* Q = qb + (size_t)bh * NSEQ * DH;
    const ushort* K = kb + (size_t)bh * NSEQ * DH;
    const ushort* V = vt + (size_t)bh * DH * NSEQ;   // [DH][NSEQ]

    bf16x8 qf[2][2];
#pragma unroll
    for (int m = 0; m < 2; m++) {
        const ushort* qrow = Q + (size_t)(qt*128 + w*32 + m*16 + c)*DH + quad*8;
        qf[m][0] = *(const bf16x8*)(qrow);
        qf[m][1] = *(const bf16x8*)(qrow + 32);
    }

    f32x4 Oacc[2][4] = {};
    float lsum[2][4] = {};

    auto stage = [&](int kt, int buf) {
#pragma unroll
        for (int u = 0; u < 2; u++) {            // K segs
            const int seg = w + u*4;             // 0..7
            const int nt = seg >> 1, hh = seg & 1;
            const ushort* g = K + (size_t)(kt*64 + nt*16 + c)*DH + hh*32 + quad*8;
            async16(g, smem + buf*16384 + seg*1024);
        }
#pragma unroll
        for (int u = 0; u < 2; u++) {            // V segs
            const int s2 = w + u*4;              // 0..7
            const int nt = s2 >> 1, kc = s2 & 1;
            const ushort* g = V + (size_t)(nt*16 + c)*NSEQ + kt*64 + kc*32 + quad*8;
            async16(g, smem + buf*16384 + 8192 + s2*1024);
        }
    };

    stage(0, 0);

    for (int kt = 0; kt < 16; kt++) {
        const int cur = kt & 1, nxt = cur ^ 1;
        if (kt < 15) {
            stage(kt+1, nxt);
            // wait only kt's 4 DMAs (oldest); kt+1's 4 stay in flight
            __asm__ volatile("s_waitcnt vmcnt(4)\n\ts_barrier" ::: "memory");
        } else {
            __asm__ volatile("s_waitcnt vmcnt(0)\n\ts_barrier" ::: "memory");
        }

        const char* Kb = smem + cur*16384;
        const char* Vb = smem + cur*16384 + 8192;

        f32x4 s[2][4];
#pragma unroll
        for (int nt = 0; nt < 4; nt++) {
            bf16x8 k0 = *(const bf16x8*)(Kb + (nt*2+0)*1024 + lane*16);
            bf16x8 k1 = *(const bf16x8*)(Kb + (nt*2+1)*1024 + lane*16);
#pragma unroll
            for (int m = 0; m < 2; m++) {
                f32x4 a = {0.f, 0.f, 0.f, 0.f};
                a = __builtin_amdgcn_mfma_f32_16x16x32_bf16(qf[m][0], k0, a, 0, 0, 0);
                a = __builtin_amdgcn_mfma_f32_16x16x32_bf16(qf[m][1], k1, a, 0, 0, 0);
                s[m][nt] = a;
            }
        }

#pragma unroll
        for (int m = 0; m < 2; m++) {
            ushort (*Psw)[72] = (ushort (*)[72])(smem + 32768 + (w*2+m)*2304);
#pragma unroll
            for (int nt = 0; nt < 4; nt++)
#pragma unroll
                for (int r = 0; r < 4; r++) {
                    const float p = exp2f(s[m][nt][r]);
                    lsum[m][r] += p;
                    Psw[quad*4 + r][nt*16 + c] = (ushort)__builtin_bit_cast(
                        unsigned short, (__bf16)p);
                }
        }
        __asm__ volatile("s_waitcnt lgkmcnt(0)" ::: "memory");

#pragma unroll
        for (int kc = 0; kc < 2; kc++) {
            bf16x8 vfr[4];
#pragma unroll
            for (int nt = 0; nt < 4; nt++)
                vfr[nt] = *(const bf16x8*)(Vb + (nt*2+kc)*1024 + lane*16);
#pragma unroll
            for (int m = 0; m < 2; m++) {
                ushort (*Psw)[72] = (ushort (*)[72])(smem + 32768 + (w*2+m)*2304);
                bf16x8 a = *(const bf16x8*)&Psw[c][kc*32 + quad*8];
#pragma unroll
                for (int nt = 0; nt < 4; nt++)
                    Oacc[m][nt] = __builtin_amdgcn_mfma_f32_16x16x32_bf16(
                        a, vfr[nt], Oacc[m][nt], 0, 0, 0);
            }
        }
        // LDS reads retired before next iteration's DMAs overwrite cur
        __asm__ volatile("s_waitcnt lgkmcnt(0)\n\ts_barrier" ::: "memory");
    }

#pragma unroll
    for (int mk = 1; mk < 16; mk <<= 1)
#pragma unroll
        for (int m = 0; m < 2; m++)
#pragma unroll
            for (int r = 0; r < 4; r++)
                lsum[m][r] += __shfl_xor(lsum[m][r], mk);

    __syncthreads();
    float (*Osh)[68] = (float (*)[68])smem;   // [128][68]
    {
        float inv[2][4];
#pragma unroll
        for (int m = 0; m < 2; m++)
#pragma unroll
            for (int r = 0; r < 4; r++) inv[m][r] = 1.f / lsum[m][r];
#pragma unroll
        for (int m = 0; m < 2; m++)
#pragma unroll
            for (int nt = 0; nt < 4; nt++)
#pragma unroll
                for (int r = 0; r < 4; r++)
                    Osh[w*32 + m*16 + quad*4 + r][nt*16 + c] =
                        Oacc[m][nt][r] * inv[m][r];
    }
    __syncthreads();

#pragma unroll
    for (int u = 0; u < 8; u++) {
        const int t   = tid + u*256;       // 0..2047
        const int row = t >> 4;            // 0..127
        const int g   = t & 15;
        const int n   = qt*128 + row;
        const float o0 = Osh[row][g*4+0], o1 = Osh[row][g*4+1];
        const float o2 = Osh[row][g*4+2], o3 = Osh[row][g*4+3];
        const float* R = rot   + (size_t)(bb*NSEQ + n)*9;
        const float* T = trans + (size_t)(bb*NSEQ + n)*3;
        const float ti0 = -(R[0]*T[0] + R[3]*T[1] + R[6]*T[2]);
        const float ti1 = -(R[1]*T[0] + R[4]*T[1] + R[7]*T[2]);
        const float ti2 = -(R[2]*T[0] + R[5]*T[1] + R[8]*T[2]);
        const float p0 = R[0]*o0 + R[3]*o1 + R[6]*o2 + ti0*o3;
        const float p1 = R[1]*o0 + R[4]*o1 + R[7]*o2 + ti1*o3;
        const float p2 = R[2]*o0 + R[5]*o1 + R[8]*o2 + ti2*o3;
        const float p3 = o3;
        ushort4 hv, lv;
        split2(p0, hv.x, lv.x); split2(p1, hv.y, lv.y);
        split2(p2, hv.z, lv.z); split2(p3, hv.w, lv.w);
        const size_t idx = (size_t)(bb*NSEQ + n)*INNER + h*DH + g*4;
        *(ushort4*)(omh + idx) = hv;
        *(ushort4*)(oml + idx) = lv;
    }
}

// ---------------------------------------------------------------------------
// Kernel 3: out^T MFMA GEMM: C = woT_bf16 * (omh + oml), 2 passes, 3 staged
// parts, fine-grained vmcnt pipeline (R11, unchanged).
// ---------------------------------------------------------------------------
__global__ __launch_bounds__(256) void out_gemm_split(
    const ushort* __restrict__ Agh, const ushort* __restrict__ Bgh,
    const ushort* __restrict__ Bgl,
    const float* __restrict__ bias, float* __restrict__ out)
{
    extern __shared__ __align__(16) char smem[];   // 49152 B

    const int tid  = threadIdx.x;
    const int lane = tid & 63;
    const int w    = tid >> 6;
    const int c    = lane & 15;
    const int quad = lane >> 4;
    const int wr   = w >> 1, wc = w & 1;
    const int tn   = blockIdx.x;   // token tile (64)
    const int tf   = blockIdx.y;   // feature tile (4)

    f32x4 acc[4][4] = {};

    const ushort* wp = (w == 0) ? Agh : (w == 1) ? Bgh : Bgl;
    const ushort* wbase = wp + (size_t)((w == 0 ? tf : tn)*128 + c)*INNER + quad*8;
    const int lbase = w * 8192;

    auto stage = [&](int k0, int buf) {
        if (w < 3) {
#pragma unroll
            for (int g = 0; g < 8; g++)
                async16(wbase + (size_t)g*16*INNER + k0,
                        smem + buf*24576 + lbase + g*1024);
        }
    };

    stage(0, 0);

    for (int ch = 0; ch < 16; ch++) {
        const int cur = ch & 1, nxt = cur ^ 1;
        if (ch < 15) {
            stage((ch+1)*32, nxt);
            __asm__ volatile("s_waitcnt vmcnt(8)\n\ts_barrier" ::: "memory");
        } else {
            __asm__ volatile("s_waitcnt vmcnt(0)\n\ts_barrier" ::: "memory");
        }

        const char* B = smem + cur*24576;
        bf16x8 fa[4], fbh[4], fbl[4];
#pragma unroll
        for (int i = 0; i < 4; i++)
            fa[i] = *(const bf16x8*)(B + (wr*4 + i)*1024 + lane*16);
#pragma unroll
        for (int j = 0; j < 4; j++) {
            fbh[j] = *(const bf16x8*)(B +  8192 + (wc*4 + j)*1024 + lane*16);
            fbl[j] = *(const bf16x8*)(B + 16384 + (wc*4 + j)*1024 + lane*16);
        }
#pragma unroll
        for (int i = 0; i < 4; i++)
#pragma unroll
            for (int j = 0; j < 4; j++) {
                acc[i][j] = __builtin_amdgcn_mfma_f32_16x16x32_bf16(
                    fa[i], fbh[j], acc[i][j], 0, 0, 0);
                acc[i][j] = __builtin_amdgcn_mfma_f32_16x16x32_bf16(
                    fa[i], fbl[j], acc[i][j], 0, 0, 0);
            }
        __asm__ volatile("s_waitcnt lgkmcnt(0)\n\ts_barrier" ::: "memory");
    }

#pragma unroll
    for (int j = 0; j < 4; j++) {
        const int tc = tn*128 + wc*64 + j*16 + c;
#pragma unroll
        for (int i = 0; i < 4; i++) {
            const int fr = tf*128 + wr*64 + i*16 + quad*4;
            float4 bv = *(const float4*)(bias + fr);
            float4 ov = { acc[i][j][0] + bv.x, acc[i][j][1] + bv.y,
                          acc[i][j][2] + bv.z, acc[i][j][3] + bv.w };
            *(float4*)(out + (size_t)tc*DIM + fr) = ov;
        }
    }
}

extern "C" void kernel_launch(void* const* d_in, const int* in_sizes, int n_in,
                              void* d_out, int out_size, void* d_ws, size_t ws_size,
                              hipStream_t stream) {
    (void)in_sizes; (void)n_in; (void)out_size; (void)ws_size;
    const float* x     = (const float*)d_in[0];
    const float* rot   = (const float*)d_in[1];
    const float* trans = (const float*)d_in[2];
    const float* w_qkv = (const float*)d_in[3];
    const float* b_qkv = (const float*)d_in[4];
    const float* w_out = (const float*)d_in[5];
    const float* b_out = (const float*)d_in[6];
    float* out = (float*)d_out;

    const size_t HB = (size_t)BSZ*NH*NSEQ*DH;        // 4,194,304 elements
    ushort* qb   = (ushort*)d_ws;
    ushort* kb   = qb   + HB;
    ushort* vt   = kb   + HB;                        // [BH][DH][NSEQ]
    ushort* woTh = vt   + HB;                        // [DIM][INNER]
    ushort* wqTh = woTh + (size_t)DIM*INNER;         // [QKVN][DIM]
    ushort* xh   = wqTh + (size_t)QKVN*DIM;          // [NTOK][DIM]
    ushort* xl   = xh   + HB;
    // omh/oml reuse xh/xl (x consumed by kernel 1; om written by kernel 2)
    ushort* omh  = xh;
    ushort* oml  = xl;

    split_cvt_kernel<<<dim3(NTOK*DIM/1024), 256, 0, stream>>>(x, xh, xl);
    tconv_kernel<<<dim3(QKVN/32, DIM/32), 256, 0, stream>>>(w_qkv, wqTh, DIM, QKVN);
    tconv_kernel<<<dim3(DIM/32, INNER/32), 256, 0, stream>>>(w_out, woTh, INNER, DIM);

    qkv_gemm_split<<<dim3(NTOK/128, QKVN/128), 256, 49152, stream>>>(
        wqTh, xh, xl, b_qkv, rot, trans, qb, kb, vt);
    attn_mfma_kernel<<<dim3(NSEQ/128, BSZ*NH), 256, 0, stream>>>(
        qb, kb, vt, rot, trans, omh, oml);
    out_gemm_split<<<dim3(NTOK/128, DIM/128), 256, 49152, stream>>>(
        woTh, omh, oml, b_out, out);
}

// Round 14
// 180.056 us; speedup vs baseline: 1.1814x; 1.0232x over previous
//
#include <hip/hip_runtime.h>
#include <math.h>

#define BSZ   8
#define NSEQ  1024
#define DIM   512
#define NH    8
#define DH    64
#define INNER 512
#define NTOK  (BSZ*NSEQ)     // 8192
#define QKVN  (3*INNER)      // 1536

typedef __bf16 bf16x8 __attribute__((ext_vector_type(8)));
typedef float  f32x4  __attribute__((ext_vector_type(4)));

// q pre-scale: softmax scale (DH^-0.5 = 0.125) folded with log2(e)
#define QSCL (0.125f * 1.44269504088896f)

static __device__ __forceinline__ ushort f2bf(float f) {
    union { float f; unsigned u; } v; v.f = f;
    unsigned r = (v.u + 0x7FFFu + ((v.u >> 16) & 1u)) >> 16;  // RNE
    return (ushort)r;
}
static __device__ __forceinline__ float bf2f(ushort u) {
    union { unsigned u; float f; } v; v.u = ((unsigned)u) << 16;
    return v.f;
}
static __device__ __forceinline__ void split2(float x, ushort& h, ushort& l) {
    h = f2bf(x);
    l = f2bf(x - bf2f(h));
}
// async global->LDS DMA, 16B per lane; LDS dest = wave-uniform base + lane*16
static __device__ __forceinline__ void async16(const void* g, void* l) {
    __builtin_amdgcn_global_load_lds(
        (const __attribute__((address_space(1))) unsigned int*)g,
        (__attribute__((address_space(3))) unsigned int*)l, 16, 0, 0);
}

// ---------------------------------------------------------------------------
// Elementwise fp32 -> bf16 hi/lo split (x)
// ---------------------------------------------------------------------------
__global__ __launch_bounds__(256) void split_cvt_kernel(
    const float* __restrict__ in, ushort* __restrict__ oh, ushort* __restrict__ ol)
{
    const int i = blockIdx.x * 256 + threadIdx.x;
    float4 v = ((const float4*)in)[i];
    ushort4 h, l;
    split2(v.x, h.x, l.x); split2(v.y, h.y, l.y);
    split2(v.z, h.z, l.z); split2(v.w, h.w, l.w);
    ((ushort4*)oh)[i] = h;
    ((ushort4*)ol)[i] = l;
}

// ---------------------------------------------------------------------------
// Transpose + convert: in [K][F] fp32 row-major -> out [F][K] bf16
// ---------------------------------------------------------------------------
__global__ __launch_bounds__(256) void tconv_kernel(
    const float* __restrict__ in, ushort* __restrict__ outh, int K, int F)
{
    __shared__ float tile[32][33];
    const int bx = blockIdx.x;           // F/32
    const int by = blockIdx.y;           // K/32
    const int lx = threadIdx.x & 31, ly = threadIdx.x >> 5;
#pragma unroll
    for (int u = 0; u < 4; u++) {
        const int k = by*32 + ly + u*8;
        tile[ly + u*8][lx] = in[(size_t)k*F + bx*32 + lx];
    }
    __syncthreads();
#pragma unroll
    for (int u = 0; u < 4; u++) {
        const int f = bx*32 + ly + u*8;
        outh[(size_t)f*K + by*32 + lx] = f2bf(tile[lx][ly + u*8]);
    }
}

// ---------------------------------------------------------------------------
// Kernel 1: qkv^T MFMA GEMM: C = w_bf16 * (xh + xl), 2 passes, 3 staged
// parts (Ah/Bh/Bl), BK=32, fine-grained vmcnt pipeline (R11, proven).
// Epilogue: bias + SE(3) pose; q,k row-major; V written transposed to vt.
// ---------------------------------------------------------------------------
__global__ __launch_bounds__(256) void qkv_gemm_split(
    const ushort* __restrict__ Agh, const ushort* __restrict__ Bgh,
    const ushort* __restrict__ Bgl,
    const float* __restrict__ bias, const float* __restrict__ rot,
    const float* __restrict__ trans,
    ushort* __restrict__ qb, ushort* __restrict__ kb, ushort* __restrict__ vt)
{
    extern __shared__ __align__(16) char smem[];   // 49152 B

    const int tid  = threadIdx.x;
    const int lane = tid & 63;
    const int w    = tid >> 6;
    const int c    = lane & 15;
    const int quad = lane >> 4;
    const int wr   = w >> 1, wc = w & 1;
    const int tn   = blockIdx.x;   // token tile (64)
    const int tf   = blockIdx.y;   // feature tile (12)

    f32x4 acc[4][4] = {};

    // wave roles: 0 -> Ah, 1 -> Bh, 2 -> Bl, 3 -> idle (issue-only staging)
    const ushort* wp = (w == 0) ? Agh : (w == 1) ? Bgh : Bgl;
    const ushort* wbase = wp + (size_t)((w == 0 ? tf : tn)*128 + c)*DIM + quad*8;
    const int lbase = w * 8192;    // A at 0, Bh at 8192, Bl at 16384

    auto stage = [&](int k0, int buf) {
        if (w < 3) {
#pragma unroll
            for (int g = 0; g < 8; g++)
                async16(wbase + (size_t)g*16*DIM + k0,
                        smem + buf*24576 + lbase + g*1024);
        }
    };

    stage(0, 0);

    for (int ch = 0; ch < 16; ch++) {
        const int cur = ch & 1, nxt = cur ^ 1;
        if (ch < 15) {
            stage((ch+1)*32, nxt);
            // wait only chunk-ch's 8 DMAs (oldest); ch+1's stay in flight
            __asm__ volatile("s_waitcnt vmcnt(8)\n\ts_barrier" ::: "memory");
        } else {
            __asm__ volatile("s_waitcnt vmcnt(0)\n\ts_barrier" ::: "memory");
        }

        const char* B = smem + cur*24576;
        bf16x8 fa[4], fbh[4], fbl[4];
#pragma unroll
        for (int i = 0; i < 4; i++)
            fa[i] = *(const bf16x8*)(B + (wr*4 + i)*1024 + lane*16);
#pragma unroll
        for (int j = 0; j < 4; j++) {
            fbh[j] = *(const bf16x8*)(B +  8192 + (wc*4 + j)*1024 + lane*16);
            fbl[j] = *(const bf16x8*)(B + 16384 + (wc*4 + j)*1024 + lane*16);
        }
#pragma unroll
        for (int i = 0; i < 4; i++)
#pragma unroll
            for (int j = 0; j < 4; j++) {
                acc[i][j] = __builtin_amdgcn_mfma_f32_16x16x32_bf16(
                    fa[i], fbh[j], acc[i][j], 0, 0, 0);
                acc[i][j] = __builtin_amdgcn_mfma_f32_16x16x32_bf16(
                    fa[i], fbl[j], acc[i][j], 0, 0, 0);
            }
        __asm__ volatile("s_waitcnt lgkmcnt(0)\n\ts_barrier" ::: "memory");
    }

    // epilogue: bias + SE(3) pose + scatter (verified mapping)
    const int sec = tf >> 2;          // 0=q 1=k 2=v (block-uniform)

#pragma unroll
    for (int j = 0; j < 4; j++) {
        const int tc = tn*128 + wc*64 + j*16 + c;
        const int bb = tc >> 10, n = tc & 1023;
        const float* R = rot   + (size_t)(bb*NSEQ + n)*9;
        const float* T = trans + (size_t)(bb*NSEQ + n)*3;
        const float R0=R[0],R1=R[1],R2=R[2],R3=R[3],R4=R[4],R5=R[5],R6=R[6],R7=R[7],R8=R[8];
        const float T0=T[0],T1=T[1],T2=T[2];
        float ti0 = 0.f, ti1 = 0.f, ti2 = 0.f;
        if (sec == 0) {
            ti0 = -(R0*T0 + R3*T1 + R6*T2);
            ti1 = -(R1*T0 + R4*T1 + R7*T2);
            ti2 = -(R2*T0 + R5*T1 + R8*T2);
        }
#pragma unroll
        for (int i = 0; i < 4; i++) {
            const int fr = tf*128 + wr*64 + i*16 + quad*4;
            const int fl = fr & 511;
            const int h  = fl >> 6, d = fl & 63;
            float4 bv = *(const float4*)(bias + fr);
            const float g0 = acc[i][j][0] + bv.x;
            const float g1 = acc[i][j][1] + bv.y;
            const float g2 = acc[i][j][2] + bv.z;
            const float g3 = acc[i][j][3] + bv.w;
            if (sec == 0) {
                float o0 = (R0*g0 + R1*g1 + R2*g2) * QSCL;
                float o1 = (R3*g0 + R4*g1 + R5*g2) * QSCL;
                float o2 = (R6*g0 + R7*g1 + R8*g2) * QSCL;
                float o3 = (ti0*g0 + ti1*g1 + ti2*g2 + g3) * QSCL;
                ushort4 ov = { f2bf(o0), f2bf(o1), f2bf(o2), f2bf(o3) };
                *(ushort4*)(qb + ((size_t)((bb*NH + h)*NSEQ + n))*DH + d) = ov;
            } else {
                float o0 = R0*g0 + R1*g1 + R2*g2 + T0*g3;
                float o1 = R3*g0 + R4*g1 + R5*g2 + T1*g3;
                float o2 = R6*g0 + R7*g1 + R8*g2 + T2*g3;
                float o3 = g3;
                if (sec == 1) {
                    ushort4 ov = { f2bf(o0), f2bf(o1), f2bf(o2), f2bf(o3) };
                    *(ushort4*)(kb + ((size_t)((bb*NH + h)*NSEQ + n))*DH + d) = ov;
                } else {
                    // v: write TRANSPOSED -> vt[bh][d][n]
                    ushort* vtb = vt + ((size_t)(bb*NH + h)*DH + d)*NSEQ + n;
                    vtb[0*NSEQ] = f2bf(o0);
                    vtb[1*NSEQ] = f2bf(o1);
                    vtb[2*NSEQ] = f2bf(o2);
                    vtb[3*NSEQ] = f2bf(o3);
                }
            }
        }
    }
}

// ---------------------------------------------------------------------------
// Kernel 2: async-pipelined MFMA flash attention (R13). Epilogue now writes
// om as plain bf16 (no hi/lo split) — +0.05 predicted absmax, half the
// epilogue stores, enables single-pass out-GEMM.
// ---------------------------------------------------------------------------
__global__ __launch_bounds__(256) void attn_mfma_kernel(
    const ushort* __restrict__ qb, const ushort* __restrict__ kb,
    const ushort* __restrict__ vt, const float* __restrict__ rot,
    const float* __restrict__ trans, ushort* __restrict__ om)
{
    __shared__ __align__(16) char smem[51200];

    const int tid  = threadIdx.x;
    const int lane = tid & 63;
    const int w    = tid >> 6;
    const int c    = lane & 15;
    const int quad = lane >> 4;

    const int qt = blockIdx.x;      // 0..7 (128 q rows)
    const int bh = blockIdx.y;      // 0..63
    const int bb = bh >> 3, h = bh & 7;

    const ushort* Q = qb + (size_t)bh * NSEQ * DH;
    const ushort* K = kb + (size_t)bh * NSEQ * DH;
    const ushort* V = vt + (size_t)bh * DH * NSEQ;   // [DH][NSEQ]

    bf16x8 qf[2][2];
#pragma unroll
    for (int m = 0; m < 2; m++) {
        const ushort* qrow = Q + (size_t)(qt*128 + w*32 + m*16 + c)*DH + quad*8;
        qf[m][0] = *(const bf16x8*)(qrow);
        qf[m][1] = *(const bf16x8*)(qrow + 32);
    }

    f32x4 Oacc[2][4] = {};
    float lsum[2][4] = {};

    auto stage = [&](int kt, int buf) {
#pragma unroll
        for (int u = 0; u < 2; u++) {            // K segs
            const int seg = w + u*4;             // 0..7
            const int nt = seg >> 1, hh = seg & 1;
            const ushort* g = K + (size_t)(kt*64 + nt*16 + c)*DH + hh*32 + quad*8;
            async16(g, smem + buf*16384 + seg*1024);
        }
#pragma unroll
        for (int u = 0; u < 2; u++) {            // V segs
            const int s2 = w + u*4;              // 0..7
            const int nt = s2 >> 1, kc = s2 & 1;
            const ushort* g = V + (size_t)(nt*16 + c)*NSEQ + kt*64 + kc*32 + quad*8;
            async16(g, smem + buf*16384 + 8192 + s2*1024);
        }
    };

    stage(0, 0);

    for (int kt = 0; kt < 16; kt++) {
        const int cur = kt & 1, nxt = cur ^ 1;
        if (kt < 15) {
            stage(kt+1, nxt);
            __asm__ volatile("s_waitcnt vmcnt(4)\n\ts_barrier" ::: "memory");
        } else {
            __asm__ volatile("s_waitcnt vmcnt(0)\n\ts_barrier" ::: "memory");
        }

        const char* Kb = smem + cur*16384;
        const char* Vb = smem + cur*16384 + 8192;

        f32x4 s[2][4];
#pragma unroll
        for (int nt = 0; nt < 4; nt++) {
            bf16x8 k0 = *(const bf16x8*)(Kb + (nt*2+0)*1024 + lane*16);
            bf16x8 k1 = *(const bf16x8*)(Kb + (nt*2+1)*1024 + lane*16);
#pragma unroll
            for (int m = 0; m < 2; m++) {
                f32x4 a = {0.f, 0.f, 0.f, 0.f};
                a = __builtin_amdgcn_mfma_f32_16x16x32_bf16(qf[m][0], k0, a, 0, 0, 0);
                a = __builtin_amdgcn_mfma_f32_16x16x32_bf16(qf[m][1], k1, a, 0, 0, 0);
                s[m][nt] = a;
            }
        }

#pragma unroll
        for (int m = 0; m < 2; m++) {
            ushort (*Psw)[72] = (ushort (*)[72])(smem + 32768 + (w*2+m)*2304);
#pragma unroll
            for (int nt = 0; nt < 4; nt++)
#pragma unroll
                for (int r = 0; r < 4; r++) {
                    const float p = exp2f(s[m][nt][r]);
                    lsum[m][r] += p;
                    Psw[quad*4 + r][nt*16 + c] = (ushort)__builtin_bit_cast(
                        unsigned short, (__bf16)p);
                }
        }
        __asm__ volatile("s_waitcnt lgkmcnt(0)" ::: "memory");

#pragma unroll
        for (int kc = 0; kc < 2; kc++) {
            bf16x8 vfr[4];
#pragma unroll
            for (int nt = 0; nt < 4; nt++)
                vfr[nt] = *(const bf16x8*)(Vb + (nt*2+kc)*1024 + lane*16);
#pragma unroll
            for (int m = 0; m < 2; m++) {
                ushort (*Psw)[72] = (ushort (*)[72])(smem + 32768 + (w*2+m)*2304);
                bf16x8 a = *(const bf16x8*)&Psw[c][kc*32 + quad*8];
#pragma unroll
                for (int nt = 0; nt < 4; nt++)
                    Oacc[m][nt] = __builtin_amdgcn_mfma_f32_16x16x32_bf16(
                        a, vfr[nt], Oacc[m][nt], 0, 0, 0);
            }
        }
        __asm__ volatile("s_waitcnt lgkmcnt(0)\n\ts_barrier" ::: "memory");
    }

#pragma unroll
    for (int mk = 1; mk < 16; mk <<= 1)
#pragma unroll
        for (int m = 0; m < 2; m++)
#pragma unroll
            for (int r = 0; r < 4; r++)
                lsum[m][r] += __shfl_xor(lsum[m][r], mk);

    __syncthreads();
    float (*Osh)[68] = (float (*)[68])smem;   // [128][68]
    {
        float inv[2][4];
#pragma unroll
        for (int m = 0; m < 2; m++)
#pragma unroll
            for (int r = 0; r < 4; r++) inv[m][r] = 1.f / lsum[m][r];
#pragma unroll
        for (int m = 0; m < 2; m++)
#pragma unroll
            for (int nt = 0; nt < 4; nt++)
#pragma unroll
                for (int r = 0; r < 4; r++)
                    Osh[w*32 + m*16 + quad*4 + r][nt*16 + c] =
                        Oacc[m][nt][r] * inv[m][r];
    }
    __syncthreads();

#pragma unroll
    for (int u = 0; u < 8; u++) {
        const int t   = tid + u*256;       // 0..2047
        const int row = t >> 4;            // 0..127
        const int g   = t & 15;
        const int n   = qt*128 + row;
        const float o0 = Osh[row][g*4+0], o1 = Osh[row][g*4+1];
        const float o2 = Osh[row][g*4+2], o3 = Osh[row][g*4+3];
        const float* R = rot   + (size_t)(bb*NSEQ + n)*9;
        const float* T = trans + (size_t)(bb*NSEQ + n)*3;
        const float ti0 = -(R[0]*T[0] + R[3]*T[1] + R[6]*T[2]);
        const float ti1 = -(R[1]*T[0] + R[4]*T[1] + R[7]*T[2]);
        const float ti2 = -(R[2]*T[0] + R[5]*T[1] + R[8]*T[2]);
        const float p0 = R[0]*o0 + R[3]*o1 + R[6]*o2 + ti0*o3;
        const float p1 = R[1]*o0 + R[4]*o1 + R[7]*o2 + ti1*o3;
        const float p2 = R[2]*o0 + R[5]*o1 + R[8]*o2 + ti2*o3;
        const float p3 = o3;
        ushort4 hv = { f2bf(p0), f2bf(p1), f2bf(p2), f2bf(p3) };
        *(ushort4*)(om + (size_t)(bb*NSEQ + n)*INNER + h*DH + g*4) = hv;
    }
}

// ---------------------------------------------------------------------------
// Kernel 3: out^T single-pass bf16 MFMA GEMM: C = woT_bf16 * om_bf16.
// 2 staged parts (A,B) = 16 KB/chunk, BK=32, all 4 waves stage (4 DMAs
// each, vmcnt(4)), LDS 32KB. Epilogue: + bias, fp32 store.
// ---------------------------------------------------------------------------
__global__ __launch_bounds__(256) void out_gemm_mfma(
    const ushort* __restrict__ Ag, const ushort* __restrict__ Bg,
    const float* __restrict__ bias, float* __restrict__ out)
{
    extern __shared__ __align__(16) char smem[];   // 32768 B

    const int tid  = threadIdx.x;
    const int lane = tid & 63;
    const int w    = tid >> 6;
    const int c    = lane & 15;
    const int quad = lane >> 4;
    const int wr   = w >> 1, wc = w & 1;
    const int tn   = blockIdx.x;   // token tile (64)
    const int tf   = blockIdx.y;   // feature tile (4)

    f32x4 acc[4][4] = {};

    // staging roles: part = w>>1 (0=A,1=B), group base = (w&1)*4
    const int part = w >> 1;
    const int g0   = (w & 1) * 4;
    const ushort* src = (part == 0) ? Ag : Bg;
    const ushort* wbase = src + (size_t)((part == 0 ? tf : tn)*128 + g0*16 + c)*INNER
                          + quad*8;

    auto stage = [&](int k0, int buf) {
#pragma unroll
        for (int g = 0; g < 4; g++)
            async16(wbase + (size_t)g*16*INNER + k0,
                    smem + buf*16384 + part*8192 + (g0 + g)*1024);
    };

    stage(0, 0);

    for (int ch = 0; ch < 16; ch++) {
        const int cur = ch & 1, nxt = cur ^ 1;
        if (ch < 15) {
            stage((ch+1)*32, nxt);
            __asm__ volatile("s_waitcnt vmcnt(4)\n\ts_barrier" ::: "memory");
        } else {
            __asm__ volatile("s_waitcnt vmcnt(0)\n\ts_barrier" ::: "memory");
        }

        const char* B = smem + cur*16384;
        bf16x8 fa[4], fb[4];
#pragma unroll
        for (int i = 0; i < 4; i++)
            fa[i] = *(const bf16x8*)(B + (wr*4 + i)*1024 + lane*16);
#pragma unroll
        for (int j = 0; j < 4; j++)
            fb[j] = *(const bf16x8*)(B + 8192 + (wc*4 + j)*1024 + lane*16);
#pragma unroll
        for (int i = 0; i < 4; i++)
#pragma unroll
            for (int j = 0; j < 4; j++)
                acc[i][j] = __builtin_amdgcn_mfma_f32_16x16x32_bf16(
                    fa[i], fb[j], acc[i][j], 0, 0, 0);
        __asm__ volatile("s_waitcnt lgkmcnt(0)\n\ts_barrier" ::: "memory");
    }

#pragma unroll
    for (int j = 0; j < 4; j++) {
        const int tc = tn*128 + wc*64 + j*16 + c;
#pragma unroll
        for (int i = 0; i < 4; i++) {
            const int fr = tf*128 + wr*64 + i*16 + quad*4;
            float4 bv = *(const float4*)(bias + fr);
            float4 ov = { acc[i][j][0] + bv.x, acc[i][j][1] + bv.y,
                          acc[i][j][2] + bv.z, acc[i][j][3] + bv.w };
            *(float4*)(out + (size_t)tc*DIM + fr) = ov;
        }
    }
}

extern "C" void kernel_launch(void* const* d_in, const int* in_sizes, int n_in,
                              void* d_out, int out_size, void* d_ws, size_t ws_size,
                              hipStream_t stream) {
    (void)in_sizes; (void)n_in; (void)out_size; (void)ws_size;
    const float* x     = (const float*)d_in[0];
    const float* rot   = (const float*)d_in[1];
    const float* trans = (const float*)d_in[2];
    const float* w_qkv = (const float*)d_in[3];
    const float* b_qkv = (const float*)d_in[4];
    const float* w_out = (const float*)d_in[5];
    const float* b_out = (const float*)d_in[6];
    float* out = (float*)d_out;

    const size_t HB = (size_t)BSZ*NH*NSEQ*DH;        // 4,194,304 elements
    ushort* qb   = (ushort*)d_ws;
    ushort* kb   = qb   + HB;
    ushort* vt   = kb   + HB;                        // [BH][DH][NSEQ]
    ushort* woTh = vt   + HB;                        // [DIM][INNER]
    ushort* wqTh = woTh + (size_t)DIM*INNER;         // [QKVN][DIM]
    ushort* xh   = wqTh + (size_t)QKVN*DIM;          // [NTOK][DIM]
    ushort* xl   = xh   + HB;
    // om reuses xh (x consumed by kernel 1; om written by kernel 2)
    ushort* om   = xh;

    split_cvt_kernel<<<dim3(NTOK*DIM/1024), 256, 0, stream>>>(x, xh, xl);
    tconv_kernel<<<dim3(QKVN/32, DIM/32), 256, 0, stream>>>(w_qkv, wqTh, DIM, QKVN);
    tconv_kernel<<<dim3(DIM/32, INNER/32), 256, 0, stream>>>(w_out, woTh, INNER, DIM);

    qkv_gemm_split<<<dim3(NTOK/128, QKVN/128), 256, 49152, stream>>>(
        wqTh, xh, xl, b_qkv, rot, trans, qb, kb, vt);
    attn_mfma_kernel<<<dim3(NSEQ/128, BSZ*NH), 256, 0, stream>>>(
        qb, kb, vt, rot, trans, om);
    out_gemm_mfma<<<dim3(NTOK/128, DIM/128), 256, 32768, stream>>>(
        woTh, om, b_out, out);
}